// Round 6
// baseline (2195.326 us; speedup 1.0000x reference)
//
#include <hip/hip_runtime.h>
#include <hip/hip_bf16.h>
#include <math.h>

// Problem constants (fixed by reference)
constexpr int N_NODES = 100000;
constexpr int N_EDGES = 1600000;
constexpr int IN_CH   = 61;
constexpr float BN_EPS = 1e-5f;
constexpr int NPART   = 32;   // atomic spread slots

// stats layout (floats), total 4352:
//  [0..63]    mu_h        [64..127] rs_h
//  [128] gmu  [129] grs
//  [192 ..)   part_h: slot s -> [192+s*128+c]=sum_c, [+64+c]=sumsq_c
//  [4288 ..)  part_g: slot s -> [4288+2s]=sum, [4288+2s+1]=sumsq
constexpr int S_PH = 192;
constexpr int S_PG = 192 + NPART * 128;      // 4288
constexpr int S_TOT = S_PG + NPART * 2;      // 4352

__device__ __forceinline__ float silu(float x) { return x / (1.0f + expf(-x)); }

__device__ __forceinline__ float bf2f(unsigned v) { return __uint_as_float(v << 16); }
__device__ __forceinline__ unsigned f2bf(float f) {
    unsigned u = __float_as_uint(f);
    return (u + 0x7FFFu + ((u >> 16) & 1u)) >> 16;   // RNE
}

// Per-edge gather + [1x64]x[64x64] matvec, NO f[] array (rule #20: runtime-indexed
// arrays go to scratch — this was the 387us / 800MB-spill bug). fk is a scalar temp;
// acc[64] is statically indexed -> registers.
__device__ __forceinline__ bool edge_gemm(
    int e, const float* __restrict__ x, const float* __restrict__ pos,
    const int* __restrict__ ei, const float* __restrict__ W1,
    const float* __restrict__ b1, float* acc, int* jd_out)
{
    int js = ei[e];
    int jd = ei[N_EDGES + e];
    *jd_out = jd;
    bool valid = ((unsigned)js < (unsigned)N_NODES) && ((unsigned)jd < (unsigned)N_NODES);
    if (!valid) {
        #pragma unroll
        for (int c = 0; c < 64; ++c) acc[c] = 0.0f;
        return false;
    }
    #pragma unroll
    for (int c = 0; c < 64; ++c) acc[c] = b1[c];

    const float* xr = x + (size_t)js * IN_CH;
    #pragma unroll 4
    for (int k = 0; k < IN_CH; ++k) {
        float fk = xr[k];                      // scalar temp, no array
        #pragma unroll
        for (int c = 0; c < 64; ++c) acc[c] += fk * W1[k * 64 + c];
    }
    #pragma unroll
    for (int j = 0; j < 3; ++j) {
        float fk = pos[js * 3 + j] - pos[jd * 3 + j];
        #pragma unroll
        for (int c = 0; c < 64; ++c) acc[c] += fk * W1[(IN_CH + j) * 64 + c];
    }
    return true;
}

// ---- K0: init stats + deg ----
__global__ __launch_bounds__(256) void k_init(float* stats, int* deg) {
    int i = blockIdx.x * 256 + threadIdx.x;
    if (i < S_TOT) stats[i] = 0.0f;
    if (i < N_NODES) deg[i] = 0;
}

// ---- K1: per-edge GEMM. MODE 0: f32 h. MODE 1: bf16 h. MODE 2: stats only. ----
template<int MODE>
__global__ __launch_bounds__(256, 4) void k_edge(
    const float* __restrict__ x, const float* __restrict__ pos,
    const int* __restrict__ ei, const float* __restrict__ W1,
    const float* __restrict__ b1, float* __restrict__ stats,
    int* __restrict__ deg, void* __restrict__ h, size_t h_cap)
{
    int e = blockIdx.x * 256 + threadIdx.x;   // grid exact: E/256
    float acc[64];
    int jd;
    bool valid = edge_gemm(e, x, pos, ei, W1, b1, acc, &jd);
    if (valid) atomicAdd(&deg[jd], 1);

    if constexpr (MODE == 0) {
        if ((size_t)(e + 1) * 256 <= h_cap) {
            float4* hp = (float4*)((char*)h + (size_t)e * 256);
            #pragma unroll
            for (int i = 0; i < 16; ++i)
                hp[i] = make_float4(acc[4*i], acc[4*i+1], acc[4*i+2], acc[4*i+3]);
        }
    } else if constexpr (MODE == 1) {
        if ((size_t)(e + 1) * 128 <= h_cap) {
            unsigned wb[32];
            #pragma unroll
            for (int i = 0; i < 32; ++i)
                wb[i] = f2bf(acc[2*i]) | (f2bf(acc[2*i+1]) << 16);
            uint4* hp = (uint4*)((char*)h + (size_t)e * 128);
            #pragma unroll
            for (int j = 0; j < 8; ++j)
                hp[j] = make_uint4(wb[4*j], wb[4*j+1], wb[4*j+2], wb[4*j+3]);
        }
    } else {
        __shared__ float ls[128];
        if (threadIdx.x < 128) ls[threadIdx.x] = 0.0f;
        __syncthreads();
        #pragma unroll
        for (int c = 0; c < 64; ++c) {
            atomicAdd(&ls[c], acc[c]);
            atomicAdd(&ls[64 + c], acc[c] * acc[c]);
        }
        __syncthreads();
        if (threadIdx.x < 128)
            atomicAdd(&stats[S_PH + (blockIdx.x & (NPART-1)) * 128 + threadIdx.x],
                      ls[threadIdx.x]);
    }
}

// ---- K2: per-channel sum/sumsq streaming over h (modes 0/1 only) ----
template<int MODE>
__global__ __launch_bounds__(256) void k_stats(const void* __restrict__ h,
                                               float* __restrict__ stats)
{
    constexpr int VEC = (MODE == 0) ? 4 : 8;
    const size_t nvec = (size_t)N_EDGES * 64 / VEC;
    size_t stride = (size_t)gridDim.x * 256;
    size_t g0 = (size_t)blockIdx.x * 256 + threadIdx.x;
    int c0 = (int)((g0 * VEC) & 63);
    float sum[VEC], sq[VEC];
    #pragma unroll
    for (int j = 0; j < VEC; ++j) { sum[j] = 0.0f; sq[j] = 0.0f; }

    for (size_t v = g0; v < nvec; v += stride) {
        float vals[VEC];
        if constexpr (MODE == 0) {
            float4 t = ((const float4*)h)[v];
            vals[0] = t.x; vals[1] = t.y; vals[2] = t.z; vals[3] = t.w;
        } else {
            uint4 t = ((const uint4*)h)[v];
            vals[0] = bf2f(t.x & 0xFFFF); vals[1] = bf2f(t.x >> 16);
            vals[2] = bf2f(t.y & 0xFFFF); vals[3] = bf2f(t.y >> 16);
            vals[4] = bf2f(t.z & 0xFFFF); vals[5] = bf2f(t.z >> 16);
            vals[6] = bf2f(t.w & 0xFFFF); vals[7] = bf2f(t.w >> 16);
        }
        #pragma unroll
        for (int j = 0; j < VEC; ++j) { sum[j] += vals[j]; sq[j] += vals[j] * vals[j]; }
    }
    __shared__ float ls[128];
    if (threadIdx.x < 128) ls[threadIdx.x] = 0.0f;
    __syncthreads();
    #pragma unroll
    for (int j = 0; j < VEC; ++j) {
        atomicAdd(&ls[c0 + j], sum[j]);
        atomicAdd(&ls[64 + c0 + j], sq[j]);
    }
    __syncthreads();
    if (threadIdx.x < 128)
        atomicAdd(&stats[S_PH + (blockIdx.x & (NPART-1)) * 128 + threadIdx.x],
                  ls[threadIdx.x]);
}

// ---- K3: reduce part_h -> mu/rs ----
__global__ void k_bnfin(float* stats) {
    int c = threadIdx.x;
    if (c < 64) {
        float s = 0.0f, q = 0.0f;
        #pragma unroll
        for (int p = 0; p < NPART; ++p) {
            s += stats[S_PH + p * 128 + c];
            q += stats[S_PH + p * 128 + 64 + c];
        }
        float m = s / (float)N_EDGES;
        float v = q / (float)N_EDGES - m * m;
        stats[c] = m;
        stats[64 + c] = rsqrtf(v + BN_EPS);
    }
}

// ---- K4: gate_lin per edge + gate batch stats ----
template<int MODE>
__global__ __launch_bounds__(256) void k_gate(
    const void* __restrict__ h, const float* __restrict__ x,
    const float* __restrict__ pos, const int* __restrict__ ei,
    const float* __restrict__ W1, const float* __restrict__ b1,
    float* __restrict__ stats, const float* __restrict__ g1,
    const float* __restrict__ be1, const float* __restrict__ Wg,
    const float* __restrict__ bg, float* __restrict__ gate_lin, size_t h_cap)
{
    int e = blockIdx.x * 256 + threadIdx.x;   // grid exact
    float hv[64];
    if constexpr (MODE == 0) {
        if ((size_t)(e + 1) * 256 <= h_cap) {
            const float4* hp = (const float4*)((const char*)h + (size_t)e * 256);
            #pragma unroll
            for (int i = 0; i < 16; ++i) {
                float4 t = hp[i];
                hv[4*i] = t.x; hv[4*i+1] = t.y; hv[4*i+2] = t.z; hv[4*i+3] = t.w;
            }
        } else {
            #pragma unroll
            for (int c = 0; c < 64; ++c) hv[c] = 0.0f;
        }
    } else if constexpr (MODE == 1) {
        if ((size_t)(e + 1) * 128 <= h_cap) {
            const uint4* hp = (const uint4*)((const char*)h + (size_t)e * 128);
            #pragma unroll
            for (int j = 0; j < 8; ++j) {
                uint4 t = hp[j];
                hv[8*j+0] = bf2f(t.x & 0xFFFF); hv[8*j+1] = bf2f(t.x >> 16);
                hv[8*j+2] = bf2f(t.y & 0xFFFF); hv[8*j+3] = bf2f(t.y >> 16);
                hv[8*j+4] = bf2f(t.z & 0xFFFF); hv[8*j+5] = bf2f(t.z >> 16);
                hv[8*j+6] = bf2f(t.w & 0xFFFF); hv[8*j+7] = bf2f(t.w >> 16);
            }
        } else {
            #pragma unroll
            for (int c = 0; c < 64; ++c) hv[c] = 0.0f;
        }
    } else {
        int jd;
        edge_gemm(e, x, pos, ei, W1, b1, hv, &jd);
    }

    float gl = bg[0];
    #pragma unroll
    for (int c = 0; c < 64; ++c) {
        float t = (hv[c] - stats[c]) * stats[64 + c] * g1[c] + be1[c];
        gl += silu(t) * Wg[c];
    }
    gate_lin[e] = gl;

    float s1 = gl, s2 = gl * gl;
    #pragma unroll
    for (int off = 32; off >= 1; off >>= 1) {
        s1 += __shfl_xor(s1, off);
        s2 += __shfl_xor(s2, off);
    }
    __shared__ float red[8];
    int w = threadIdx.x >> 6, lane = threadIdx.x & 63;
    if (lane == 0) { red[w] = s1; red[4 + w] = s2; }
    __syncthreads();
    if (threadIdx.x == 0) {
        int slot = S_PG + (blockIdx.x & (NPART-1)) * 2;
        atomicAdd(&stats[slot], red[0] + red[1] + red[2] + red[3]);
        atomicAdd(&stats[slot + 1], red[4] + red[5] + red[6] + red[7]);
    }
}

// ---- K5: reduce part_g -> gmu/grs ----
__global__ void k_gfin(float* stats) {
    if (threadIdx.x == 0) {
        float s = 0.0f, q = 0.0f;
        for (int p = 0; p < NPART; ++p) {
            s += stats[S_PG + 2 * p];
            q += stats[S_PG + 2 * p + 1];
        }
        float m = s / (float)N_EDGES;
        float v = q / (float)N_EDGES - m * m;
        stats[128] = m;
        stats[129] = rsqrtf(v + BN_EPS);
    }
}

// ---- K6: single-block scan deg -> offs, cursor ----
__global__ __launch_bounds__(1024) void k_scan(const int* __restrict__ deg,
                                               int* __restrict__ offs,
                                               int* __restrict__ cursor)
{
    __shared__ int ps[1024];
    int t = threadIdx.x;
    const int CH = (N_NODES + 1023) / 1024;
    int lo = t * CH, hi = lo + CH;
    if (hi > N_NODES) hi = N_NODES;
    if (lo > N_NODES) lo = N_NODES;
    int s = 0;
    for (int i = lo; i < hi; ++i) s += deg[i];
    ps[t] = s;
    __syncthreads();
    for (int off = 1; off < 1024; off <<= 1) {
        int v = (t >= off) ? ps[t - off] : 0;
        __syncthreads();
        ps[t] += v;
        __syncthreads();
    }
    int run = (t == 0) ? 0 : ps[t - 1];
    for (int i = lo; i < hi; ++i) {
        offs[i] = run;
        cursor[i] = run;
        run += deg[i];
    }
    if (t == 1023) offs[N_NODES] = ps[1023];
}

// ---- K7: CSR fill ----
__global__ __launch_bounds__(256) void k_fill(const int* __restrict__ ei,
                                              int* __restrict__ cursor,
                                              int* __restrict__ elist)
{
    int e = blockIdx.x * 256 + threadIdx.x;
    int js = ei[e];
    int d = ei[N_EDGES + e];
    if ((unsigned)js >= (unsigned)N_NODES || (unsigned)d >= (unsigned)N_NODES) return;
    int p = atomicAdd(&cursor[d], 1);
    if ((unsigned)p < (unsigned)N_EDGES) elist[p] = e;
}

// ---- K8: wave per node, lane = channel; 1-deep software pipeline (modes 0/1) ----
template<int MODE>
__device__ __forceinline__ void aggr_body(
    const void* __restrict__ h, size_t h_cap, const float* __restrict__ gate_lin,
    const int* __restrict__ offs, const int* __restrict__ elist,
    const int* __restrict__ ei, const float* __restrict__ x,
    const float* __restrict__ pos, const float* __restrict__ b1,
    const float* W1s, const float* __restrict__ stats,
    const float* __restrict__ g1, const float* __restrict__ be1,
    const float* __restrict__ gg, const float* __restrict__ bgb,
    float* __restrict__ out)
{
    int wid = (blockIdx.x * 256 + threadIdx.x) >> 6;
    int lane = threadIdx.x & 63;
    if (wid >= N_NODES) return;

    float mu = stats[lane], rs = stats[64 + lane];
    float gmu = stats[128], grs = stats[129];
    float ga = g1[lane], bb = be1[lane];
    float gga = gg[0], gbb = bgb[0];

    int lo = offs[wid], hi = offs[wid + 1];
    float accv = 0.0f, wsum = 0.0f;

    if constexpr (MODE == 2) {
        float b1v = b1[lane];
        float pim = (lane >= IN_CH) ? pos[wid * 3 + (lane - IN_CH)] : 0.0f;
        for (int i = lo; i < hi; ++i) {
            int e = elist[i];
            float gl = gate_lin[e];
            float tg = (gl - gmu) * grs * gga + gbb;
            float w = expf(silu(tg));
            int js = ei[e];
            if ((unsigned)js >= (unsigned)N_NODES) continue;
            float fl = (lane < IN_CH) ? x[(size_t)js * IN_CH + lane]
                                      : pos[js * 3 + (lane - IN_CH)] - pim;
            float a = b1v;
            #pragma unroll
            for (int k = 0; k < 64; ++k) a += __shfl(fl, k) * W1s[k * 64 + lane];
            float tn = (a - mu) * rs * ga + bb;
            accv += w * silu(tn);
            wsum += w;
        }
    } else {
        auto load_h = [&](int e) -> float {
            if constexpr (MODE == 0) {
                if ((size_t)(e + 1) * 256 > h_cap) return 0.0f;
                return ((const float*)h)[(size_t)e * 64 + lane];
            } else {
                if ((size_t)(e + 1) * 128 > h_cap) return 0.0f;
                return bf2f(((const unsigned short*)h)[(size_t)e * 64 + lane]);
            }
        };
        if (lo < hi) {
            int e = elist[lo];
            float gl = gate_lin[e];
            float hval = load_h(e);
            for (int i = lo; i < hi; ++i) {
                int en = 0; float gln = 0.0f, hn = 0.0f;
                if (i + 1 < hi) {            // prefetch next edge while computing
                    en = elist[i + 1];
                    gln = gate_lin[en];
                    hn = load_h(en);
                }
                float tg = (gl - gmu) * grs * gga + gbb;
                float w = expf(silu(tg));    // BN-standardized: no max-shift needed
                float tn = (hval - mu) * rs * ga + bb;
                accv += w * silu(tn);
                wsum += w;
                e = en; gl = gln; hval = hn;
            }
        }
    }
    out[(size_t)wid * 64 + lane] = accv / (wsum + 1e-16f);
}

template<int MODE>
__global__ __launch_bounds__(256) void k_aggr(
    const void* __restrict__ h, size_t h_cap, const float* __restrict__ gate_lin,
    const int* __restrict__ offs, const int* __restrict__ elist,
    const int* __restrict__ ei, const float* __restrict__ x,
    const float* __restrict__ pos, const float* __restrict__ b1,
    const float* __restrict__ W1, const float* __restrict__ stats,
    const float* __restrict__ g1, const float* __restrict__ be1,
    const float* __restrict__ gg, const float* __restrict__ bgb,
    float* __restrict__ out)
{
    if constexpr (MODE == 2) {
        __shared__ float W1s[4096];
        for (int i = threadIdx.x; i < 4096; i += 256) W1s[i] = W1[i];
        __syncthreads();
        aggr_body<2>(h, h_cap, gate_lin, offs, elist, ei, x, pos, b1, W1s,
                     stats, g1, be1, gg, bgb, out);
    } else {
        aggr_body<MODE>(h, h_cap, gate_lin, offs, elist, ei, x, pos, b1, nullptr,
                        stats, g1, be1, gg, bgb, out);
    }
}

extern "C" void kernel_launch(void* const* d_in, const int* in_sizes, int n_in,
                              void* d_out, int out_size, void* d_ws, size_t ws_size,
                              hipStream_t stream)
{
    const float* x   = (const float*)d_in[0];
    const float* pos = (const float*)d_in[1];
    const int*   ei  = (const int*)d_in[2];
    const float* W1  = (const float*)d_in[3];
    const float* b1  = (const float*)d_in[4];
    const float* g1  = (const float*)d_in[5];
    const float* be1 = (const float*)d_in[6];
    const float* Wg  = (const float*)d_in[7];
    const float* bg  = (const float*)d_in[8];
    const float* gg  = (const float*)d_in[9];
    const float* bgb = (const float*)d_in[10];
    float* out = (float*)d_out;

    // --- adaptive ws layout: small structures first, h (if it fits) last ---
    char* base = (char*)d_ws;
    size_t off = 0;
    auto alloc = [&](size_t bytes) {
        size_t o = off;
        off = (off + bytes + 255) & ~(size_t)255;
        return o;
    };
    float* stats    = (float*)(base + alloc(S_TOT * 4));
    int*   deg      = (int*)(base + alloc((size_t)N_NODES * 4));
    int*   offs     = (int*)(base + alloc((size_t)(N_NODES + 1) * 4));
    int*   cursor   = (int*)(base + alloc((size_t)N_NODES * 4));
    int*   elist    = (int*)(base + alloc((size_t)N_EDGES * 4));
    float* gate_lin = (float*)(base + alloc((size_t)N_EDGES * 4));
    if (ws_size < off) return;
    void*  h     = (void*)(base + off);
    size_t h_cap = ws_size - off;

    const int mode = (h_cap >= (size_t)N_EDGES * 256) ? 0
                   : (h_cap >= (size_t)N_EDGES * 128) ? 1 : 2;

    const int EB = N_EDGES / 256;            // 6250 exact
    const int NB = (N_NODES + 255) / 256;    // 391
    const int AB = (N_NODES + 3) / 4;        // 25001

    hipLaunchKernelGGL(k_init, dim3(NB), dim3(256), 0, stream, stats, deg);

    if (mode == 0) {
        hipLaunchKernelGGL(k_edge<0>, dim3(EB), dim3(256), 0, stream,
                           x, pos, ei, W1, b1, stats, deg, h, h_cap);
        hipLaunchKernelGGL(k_stats<0>, dim3(1024), dim3(256), 0, stream, h, stats);
        hipLaunchKernelGGL(k_bnfin, dim3(1), dim3(64), 0, stream, stats);
        hipLaunchKernelGGL(k_gate<0>, dim3(EB), dim3(256), 0, stream,
                           h, x, pos, ei, W1, b1, stats, g1, be1, Wg, bg, gate_lin, h_cap);
    } else if (mode == 1) {
        hipLaunchKernelGGL(k_edge<1>, dim3(EB), dim3(256), 0, stream,
                           x, pos, ei, W1, b1, stats, deg, h, h_cap);
        hipLaunchKernelGGL(k_stats<1>, dim3(1024), dim3(256), 0, stream, h, stats);
        hipLaunchKernelGGL(k_bnfin, dim3(1), dim3(64), 0, stream, stats);
        hipLaunchKernelGGL(k_gate<1>, dim3(EB), dim3(256), 0, stream,
                           h, x, pos, ei, W1, b1, stats, g1, be1, Wg, bg, gate_lin, h_cap);
    } else {
        hipLaunchKernelGGL(k_edge<2>, dim3(EB), dim3(256), 0, stream,
                           x, pos, ei, W1, b1, stats, deg, h, h_cap);
        hipLaunchKernelGGL(k_bnfin, dim3(1), dim3(64), 0, stream, stats);
        hipLaunchKernelGGL(k_gate<2>, dim3(EB), dim3(256), 0, stream,
                           h, x, pos, ei, W1, b1, stats, g1, be1, Wg, bg, gate_lin, h_cap);
    }

    hipLaunchKernelGGL(k_gfin, dim3(1), dim3(64), 0, stream, stats);
    hipLaunchKernelGGL(k_scan, dim3(1), dim3(1024), 0, stream, deg, offs, cursor);
    hipLaunchKernelGGL(k_fill, dim3(EB), dim3(256), 0, stream, ei, cursor, elist);

    if (mode == 0) {
        hipLaunchKernelGGL(k_aggr<0>, dim3(AB), dim3(256), 0, stream,
                           h, h_cap, gate_lin, offs, elist, ei, x, pos, b1, W1,
                           stats, g1, be1, gg, bgb, out);
    } else if (mode == 1) {
        hipLaunchKernelGGL(k_aggr<1>, dim3(AB), dim3(256), 0, stream,
                           h, h_cap, gate_lin, offs, elist, ei, x, pos, b1, W1,
                           stats, g1, be1, gg, bgb, out);
    } else {
        hipLaunchKernelGGL(k_aggr<2>, dim3(AB), dim3(256), 0, stream,
                           h, h_cap, gate_lin, offs, elist, ei, x, pos, b1, W1,
                           stats, g1, be1, gg, bgb, out);
    }
}

// Round 7
// 1612.532 us; speedup vs baseline: 1.3614x; 1.3614x over previous
//
#include <hip/hip_runtime.h>
#include <hip/hip_bf16.h>
#include <math.h>

// Problem constants (fixed by reference)
constexpr int N_NODES = 100000;
constexpr int N_EDGES = 1600000;
constexpr int IN_CH   = 61;
constexpr float BN_EPS = 1e-5f;
constexpr int NPART   = 32;   // atomic spread slots

// stats layout (floats), total 4352:
//  [0..63]    mu_h        [64..127] rs_h
//  [128] gmu  [129] grs
//  [192 ..)   part_h: slot s -> [192+s*128+c]=sum_c, [+64+c]=sumsq_c
//  [4288 ..)  part_g: slot s -> [4288+2s]=sum, [4288+2s+1]=sumsq
constexpr int S_PH = 192;
constexpr int S_PG = 192 + NPART * 128;      // 4288
constexpr int S_TOT = S_PG + NPART * 2;      // 4352

__device__ __forceinline__ float silu(float x) { return x / (1.0f + expf(-x)); }

__device__ __forceinline__ float bf2f(unsigned v) { return __uint_as_float(v << 16); }
__device__ __forceinline__ unsigned f2bf(float f) {
    unsigned u = __float_as_uint(f);
    return (u + 0x7FFFu + ((u >> 16) & 1u)) >> 16;   // RNE
}

// Full-64 matvec helper — used only by MODE 2 gate/aggr fallback paths.
__device__ __forceinline__ bool edge_gemm(
    int e, const float* __restrict__ x, const float* __restrict__ pos,
    const int* __restrict__ ei, const float* __restrict__ W1,
    const float* __restrict__ b1, float* acc, int* jd_out)
{
    int js = ei[e];
    int jd = ei[N_EDGES + e];
    *jd_out = jd;
    bool valid = ((unsigned)js < (unsigned)N_NODES) && ((unsigned)jd < (unsigned)N_NODES);
    if (!valid) {
        #pragma unroll
        for (int c = 0; c < 64; ++c) acc[c] = 0.0f;
        return false;
    }
    #pragma unroll
    for (int c = 0; c < 64; ++c) acc[c] = b1[c];

    const float* xr = x + (size_t)js * IN_CH;
    #pragma unroll 4
    for (int k = 0; k < IN_CH; ++k) {
        float fk = xr[k];
        #pragma unroll
        for (int c = 0; c < 64; ++c) acc[c] += fk * W1[k * 64 + c];
    }
    #pragma unroll
    for (int j = 0; j < 3; ++j) {
        float fk = pos[js * 3 + j] - pos[jd * 3 + j];
        #pragma unroll
        for (int c = 0; c < 64; ++c) acc[c] += fk * W1[(IN_CH + j) * 64 + c];
    }
    return true;
}

// ---- K0: init stats + deg ----
__global__ __launch_bounds__(256) void k_init(float* stats, int* deg) {
    int i = blockIdx.x * 256 + threadIdx.x;
    if (i < S_TOT) stats[i] = 0.0f;
    if (i < N_NODES) deg[i] = 0;
}

// ---- K1: per-edge GEMM in TWO 32-channel passes (acc[32] -> ~55 VGPR, no spill;
//      Round-6 lesson: acc[64]=64 VGPR alone spilled, 5.6GB scratch traffic).
//      MODE 0: f32 h. MODE 1: bf16 h. MODE 2: stats only. Always: deg histogram. ----
template<int MODE>
__global__ __launch_bounds__(256) void k_edge(
    const float* __restrict__ x, const float* __restrict__ pos,
    const int* __restrict__ ei, const float* __restrict__ W1,
    const float* __restrict__ b1, float* __restrict__ stats,
    int* __restrict__ deg, void* __restrict__ h, size_t h_cap)
{
    int e = blockIdx.x * 256 + threadIdx.x;   // grid exact: E/256
    int js = ei[e];
    int jd = ei[N_EDGES + e];
    bool valid = ((unsigned)js < (unsigned)N_NODES) && ((unsigned)jd < (unsigned)N_NODES);
    if (valid) atomicAdd(&deg[jd], 1);
    int jsc = valid ? js : 0, jdc = valid ? jd : 0;
    const float* xr = x + (size_t)jsc * IN_CH;
    float p0 = pos[jsc * 3 + 0] - pos[jdc * 3 + 0];
    float p1 = pos[jsc * 3 + 1] - pos[jdc * 3 + 1];
    float p2 = pos[jsc * 3 + 2] - pos[jdc * 3 + 2];

    __shared__ float ls[128];                 // MODE 2 only
    if constexpr (MODE == 2) {
        if (threadIdx.x < 128) ls[threadIdx.x] = 0.0f;
        __syncthreads();
    }

    #pragma unroll 1                          // MUST stay 2 sequential passes
    for (int half = 0; half < 2; ++half) {
        const int base = half * 32;
        float acc[32];
        #pragma unroll
        for (int c = 0; c < 32; ++c) acc[c] = valid ? b1[base + c] : 0.0f;
        if (valid) {
            #pragma unroll 4
            for (int k = 0; k < IN_CH; ++k) {
                float fk = xr[k];             // scalar temp — never an array
                #pragma unroll
                for (int c = 0; c < 32; ++c) acc[c] += fk * W1[k * 64 + base + c];
            }
            #pragma unroll
            for (int c = 0; c < 32; ++c)
                acc[c] += p0 * W1[61 * 64 + base + c]
                        + p1 * W1[62 * 64 + base + c]
                        + p2 * W1[63 * 64 + base + c];
        }

        if constexpr (MODE == 0) {
            if ((size_t)(e + 1) * 256 <= h_cap) {
                float4* hp = (float4*)((char*)h + (size_t)e * 256 + (size_t)base * 4);
                #pragma unroll
                for (int i = 0; i < 8; ++i)
                    hp[i] = make_float4(acc[4*i], acc[4*i+1], acc[4*i+2], acc[4*i+3]);
            }
        } else if constexpr (MODE == 1) {
            if ((size_t)(e + 1) * 128 <= h_cap) {
                unsigned wb[16];
                #pragma unroll
                for (int i = 0; i < 16; ++i)
                    wb[i] = f2bf(acc[2*i]) | (f2bf(acc[2*i+1]) << 16);
                uint4* hp = (uint4*)((char*)h + (size_t)e * 128 + (size_t)base * 2);
                #pragma unroll
                for (int j = 0; j < 4; ++j)
                    hp[j] = make_uint4(wb[4*j], wb[4*j+1], wb[4*j+2], wb[4*j+3]);
            }
        } else {
            #pragma unroll
            for (int c = 0; c < 32; ++c) {
                atomicAdd(&ls[base + c], acc[c]);
                atomicAdd(&ls[64 + base + c], acc[c] * acc[c]);
            }
        }
    }

    if constexpr (MODE == 2) {
        __syncthreads();
        if (threadIdx.x < 128)
            atomicAdd(&stats[S_PH + (blockIdx.x & (NPART-1)) * 128 + threadIdx.x],
                      ls[threadIdx.x]);
    }
}

// ---- K2: per-channel sum/sumsq streaming over h (modes 0/1 only) ----
template<int MODE>
__global__ __launch_bounds__(256) void k_stats(const void* __restrict__ h,
                                               float* __restrict__ stats)
{
    constexpr int VEC = (MODE == 0) ? 4 : 8;
    const size_t nvec = (size_t)N_EDGES * 64 / VEC;
    size_t stride = (size_t)gridDim.x * 256;
    size_t g0 = (size_t)blockIdx.x * 256 + threadIdx.x;
    int c0 = (int)((g0 * VEC) & 63);
    float sum[VEC], sq[VEC];
    #pragma unroll
    for (int j = 0; j < VEC; ++j) { sum[j] = 0.0f; sq[j] = 0.0f; }

    for (size_t v = g0; v < nvec; v += stride) {
        float vals[VEC];
        if constexpr (MODE == 0) {
            float4 t = ((const float4*)h)[v];
            vals[0] = t.x; vals[1] = t.y; vals[2] = t.z; vals[3] = t.w;
        } else {
            uint4 t = ((const uint4*)h)[v];
            vals[0] = bf2f(t.x & 0xFFFF); vals[1] = bf2f(t.x >> 16);
            vals[2] = bf2f(t.y & 0xFFFF); vals[3] = bf2f(t.y >> 16);
            vals[4] = bf2f(t.z & 0xFFFF); vals[5] = bf2f(t.z >> 16);
            vals[6] = bf2f(t.w & 0xFFFF); vals[7] = bf2f(t.w >> 16);
        }
        #pragma unroll
        for (int j = 0; j < VEC; ++j) { sum[j] += vals[j]; sq[j] += vals[j] * vals[j]; }
    }
    __shared__ float ls[128];
    if (threadIdx.x < 128) ls[threadIdx.x] = 0.0f;
    __syncthreads();
    #pragma unroll
    for (int j = 0; j < VEC; ++j) {
        atomicAdd(&ls[c0 + j], sum[j]);
        atomicAdd(&ls[64 + c0 + j], sq[j]);
    }
    __syncthreads();
    if (threadIdx.x < 128)
        atomicAdd(&stats[S_PH + (blockIdx.x & (NPART-1)) * 128 + threadIdx.x],
                  ls[threadIdx.x]);
}

// ---- K3: reduce part_h -> mu/rs ----
__global__ void k_bnfin(float* stats) {
    int c = threadIdx.x;
    if (c < 64) {
        float s = 0.0f, q = 0.0f;
        #pragma unroll
        for (int p = 0; p < NPART; ++p) {
            s += stats[S_PH + p * 128 + c];
            q += stats[S_PH + p * 128 + 64 + c];
        }
        float m = s / (float)N_EDGES;
        float v = q / (float)N_EDGES - m * m;
        stats[c] = m;
        stats[64 + c] = rsqrtf(v + BN_EPS);
    }
}

// ---- K4: gate_lin per edge + gate batch stats ----
template<int MODE>
__global__ __launch_bounds__(256) void k_gate(
    const void* __restrict__ h, const float* __restrict__ x,
    const float* __restrict__ pos, const int* __restrict__ ei,
    const float* __restrict__ W1, const float* __restrict__ b1,
    float* __restrict__ stats, const float* __restrict__ g1,
    const float* __restrict__ be1, const float* __restrict__ Wg,
    const float* __restrict__ bg, float* __restrict__ gate_lin, size_t h_cap)
{
    int e = blockIdx.x * 256 + threadIdx.x;   // grid exact
    float gl = bg[0];

    if constexpr (MODE == 2) {
        float hv[64];
        int jd;
        edge_gemm(e, x, pos, ei, W1, b1, hv, &jd);
        #pragma unroll
        for (int c = 0; c < 64; ++c) {
            float t = (hv[c] - stats[c]) * stats[64 + c] * g1[c] + be1[c];
            gl += silu(t) * Wg[c];
        }
    } else if constexpr (MODE == 0) {
        if ((size_t)(e + 1) * 256 <= h_cap) {
            const float4* hp = (const float4*)((const char*)h + (size_t)e * 256);
            #pragma unroll
            for (int i = 0; i < 16; ++i) {
                float4 t = hp[i];
                float vv[4] = {t.x, t.y, t.z, t.w};
                #pragma unroll
                for (int j = 0; j < 4; ++j) {
                    int c = 4 * i + j;
                    float tt = (vv[j] - stats[c]) * stats[64 + c] * g1[c] + be1[c];
                    gl += silu(tt) * Wg[c];
                }
            }
        }
    } else {
        if ((size_t)(e + 1) * 128 <= h_cap) {
            const uint4* hp = (const uint4*)((const char*)h + (size_t)e * 128);
            #pragma unroll
            for (int j = 0; j < 8; ++j) {
                uint4 t = hp[j];
                float vv[8];
                vv[0] = bf2f(t.x & 0xFFFF); vv[1] = bf2f(t.x >> 16);
                vv[2] = bf2f(t.y & 0xFFFF); vv[3] = bf2f(t.y >> 16);
                vv[4] = bf2f(t.z & 0xFFFF); vv[5] = bf2f(t.z >> 16);
                vv[6] = bf2f(t.w & 0xFFFF); vv[7] = bf2f(t.w >> 16);
                #pragma unroll
                for (int q = 0; q < 8; ++q) {
                    int c = 8 * j + q;
                    float tt = (vv[q] - stats[c]) * stats[64 + c] * g1[c] + be1[c];
                    gl += silu(tt) * Wg[c];
                }
            }
        }
    }
    gate_lin[e] = gl;

    float s1 = gl, s2 = gl * gl;
    #pragma unroll
    for (int off = 32; off >= 1; off >>= 1) {
        s1 += __shfl_xor(s1, off);
        s2 += __shfl_xor(s2, off);
    }
    __shared__ float red[8];
    int w = threadIdx.x >> 6, lane = threadIdx.x & 63;
    if (lane == 0) { red[w] = s1; red[4 + w] = s2; }
    __syncthreads();
    if (threadIdx.x == 0) {
        int slot = S_PG + (blockIdx.x & (NPART-1)) * 2;
        atomicAdd(&stats[slot], red[0] + red[1] + red[2] + red[3]);
        atomicAdd(&stats[slot + 1], red[4] + red[5] + red[6] + red[7]);
    }
}

// ---- K5: reduce part_g -> gmu/grs ----
__global__ void k_gfin(float* stats) {
    if (threadIdx.x == 0) {
        float s = 0.0f, q = 0.0f;
        for (int p = 0; p < NPART; ++p) {
            s += stats[S_PG + 2 * p];
            q += stats[S_PG + 2 * p + 1];
        }
        float m = s / (float)N_EDGES;
        float v = q / (float)N_EDGES - m * m;
        stats[128] = m;
        stats[129] = rsqrtf(v + BN_EPS);
    }
}

// ---- K6: single-block scan deg -> offs, cursor ----
__global__ __launch_bounds__(1024) void k_scan(const int* __restrict__ deg,
                                               int* __restrict__ offs,
                                               int* __restrict__ cursor)
{
    __shared__ int ps[1024];
    int t = threadIdx.x;
    const int CH = (N_NODES + 1023) / 1024;
    int lo = t * CH, hi = lo + CH;
    if (hi > N_NODES) hi = N_NODES;
    if (lo > N_NODES) lo = N_NODES;
    int s = 0;
    for (int i = lo; i < hi; ++i) s += deg[i];
    ps[t] = s;
    __syncthreads();
    for (int off = 1; off < 1024; off <<= 1) {
        int v = (t >= off) ? ps[t - off] : 0;
        __syncthreads();
        ps[t] += v;
        __syncthreads();
    }
    int run = (t == 0) ? 0 : ps[t - 1];
    for (int i = lo; i < hi; ++i) {
        offs[i] = run;
        cursor[i] = run;
        run += deg[i];
    }
    if (t == 1023) offs[N_NODES] = ps[1023];
}

// ---- K7: CSR fill ----
__global__ __launch_bounds__(256) void k_fill(const int* __restrict__ ei,
                                              int* __restrict__ cursor,
                                              int* __restrict__ elist)
{
    int e = blockIdx.x * 256 + threadIdx.x;
    int js = ei[e];
    int d = ei[N_EDGES + e];
    if ((unsigned)js >= (unsigned)N_NODES || (unsigned)d >= (unsigned)N_NODES) return;
    int p = atomicAdd(&cursor[d], 1);
    if ((unsigned)p < (unsigned)N_EDGES) elist[p] = e;
}

// ---- K8: wave per node, lane = channel; 1-deep software pipeline (modes 0/1) ----
template<int MODE>
__device__ __forceinline__ void aggr_body(
    const void* __restrict__ h, size_t h_cap, const float* __restrict__ gate_lin,
    const int* __restrict__ offs, const int* __restrict__ elist,
    const int* __restrict__ ei, const float* __restrict__ x,
    const float* __restrict__ pos, const float* __restrict__ b1,
    const float* W1s, const float* __restrict__ stats,
    const float* __restrict__ g1, const float* __restrict__ be1,
    const float* __restrict__ gg, const float* __restrict__ bgb,
    float* __restrict__ out)
{
    int wid = (blockIdx.x * 256 + threadIdx.x) >> 6;
    int lane = threadIdx.x & 63;
    if (wid >= N_NODES) return;

    float mu = stats[lane], rs = stats[64 + lane];
    float gmu = stats[128], grs = stats[129];
    float ga = g1[lane], bb = be1[lane];
    float gga = gg[0], gbb = bgb[0];

    int lo = offs[wid], hi = offs[wid + 1];
    float accv = 0.0f, wsum = 0.0f;

    if constexpr (MODE == 2) {
        float b1v = b1[lane];
        float pim = (lane >= IN_CH) ? pos[wid * 3 + (lane - IN_CH)] : 0.0f;
        for (int i = lo; i < hi; ++i) {
            int e = elist[i];
            float gl = gate_lin[e];
            float tg = (gl - gmu) * grs * gga + gbb;
            float w = expf(silu(tg));
            int js = ei[e];
            if ((unsigned)js >= (unsigned)N_NODES) continue;
            float fl = (lane < IN_CH) ? x[(size_t)js * IN_CH + lane]
                                      : pos[js * 3 + (lane - IN_CH)] - pim;
            float a = b1v;
            #pragma unroll
            for (int k = 0; k < 64; ++k) a += __shfl(fl, k) * W1s[k * 64 + lane];
            float tn = (a - mu) * rs * ga + bb;
            accv += w * silu(tn);
            wsum += w;
        }
    } else {
        auto load_h = [&](int e) -> float {
            if constexpr (MODE == 0) {
                if ((size_t)(e + 1) * 256 > h_cap) return 0.0f;
                return ((const float*)h)[(size_t)e * 64 + lane];
            } else {
                if ((size_t)(e + 1) * 128 > h_cap) return 0.0f;
                return bf2f(((const unsigned short*)h)[(size_t)e * 64 + lane]);
            }
        };
        if (lo < hi) {
            int e = elist[lo];
            float gl = gate_lin[e];
            float hval = load_h(e);
            for (int i = lo; i < hi; ++i) {
                int en = 0; float gln = 0.0f, hn = 0.0f;
                if (i + 1 < hi) {            // prefetch next edge while computing
                    en = elist[i + 1];
                    gln = gate_lin[en];
                    hn = load_h(en);
                }
                float tg = (gl - gmu) * grs * gga + gbb;
                float w = expf(silu(tg));    // BN-standardized: no max-shift needed
                float tn = (hval - mu) * rs * ga + bb;
                accv += w * silu(tn);
                wsum += w;
                e = en; gl = gln; hval = hn;
            }
        }
    }
    out[(size_t)wid * 64 + lane] = accv / (wsum + 1e-16f);
}

template<int MODE>
__global__ __launch_bounds__(256) void k_aggr(
    const void* __restrict__ h, size_t h_cap, const float* __restrict__ gate_lin,
    const int* __restrict__ offs, const int* __restrict__ elist,
    const int* __restrict__ ei, const float* __restrict__ x,
    const float* __restrict__ pos, const float* __restrict__ b1,
    const float* __restrict__ W1, const float* __restrict__ stats,
    const float* __restrict__ g1, const float* __restrict__ be1,
    const float* __restrict__ gg, const float* __restrict__ bgb,
    float* __restrict__ out)
{
    if constexpr (MODE == 2) {
        __shared__ float W1s[4096];
        for (int i = threadIdx.x; i < 4096; i += 256) W1s[i] = W1[i];
        __syncthreads();
        aggr_body<2>(h, h_cap, gate_lin, offs, elist, ei, x, pos, b1, W1s,
                     stats, g1, be1, gg, bgb, out);
    } else {
        aggr_body<MODE>(h, h_cap, gate_lin, offs, elist, ei, x, pos, b1, nullptr,
                        stats, g1, be1, gg, bgb, out);
    }
}

extern "C" void kernel_launch(void* const* d_in, const int* in_sizes, int n_in,
                              void* d_out, int out_size, void* d_ws, size_t ws_size,
                              hipStream_t stream)
{
    const float* x   = (const float*)d_in[0];
    const float* pos = (const float*)d_in[1];
    const int*   ei  = (const int*)d_in[2];
    const float* W1  = (const float*)d_in[3];
    const float* b1  = (const float*)d_in[4];
    const float* g1  = (const float*)d_in[5];
    const float* be1 = (const float*)d_in[6];
    const float* Wg  = (const float*)d_in[7];
    const float* bg  = (const float*)d_in[8];
    const float* gg  = (const float*)d_in[9];
    const float* bgb = (const float*)d_in[10];
    float* out = (float*)d_out;

    // --- adaptive ws layout: small structures first, h (if it fits) last ---
    char* base = (char*)d_ws;
    size_t off = 0;
    auto alloc = [&](size_t bytes) {
        size_t o = off;
        off = (off + bytes + 255) & ~(size_t)255;
        return o;
    };
    float* stats    = (float*)(base + alloc(S_TOT * 4));
    int*   deg      = (int*)(base + alloc((size_t)N_NODES * 4));
    int*   offs     = (int*)(base + alloc((size_t)(N_NODES + 1) * 4));
    int*   cursor   = (int*)(base + alloc((size_t)N_NODES * 4));
    int*   elist    = (int*)(base + alloc((size_t)N_EDGES * 4));
    float* gate_lin = (float*)(base + alloc((size_t)N_EDGES * 4));
    if (ws_size < off) return;
    void*  h     = (void*)(base + off);
    size_t h_cap = ws_size - off;

    const int mode = (h_cap >= (size_t)N_EDGES * 256) ? 0
                   : (h_cap >= (size_t)N_EDGES * 128) ? 1 : 2;

    const int EB = N_EDGES / 256;            // 6250 exact
    const int NB = (N_NODES + 255) / 256;    // 391
    const int AB = (N_NODES + 3) / 4;        // 25001

    hipLaunchKernelGGL(k_init, dim3(NB), dim3(256), 0, stream, stats, deg);

    if (mode == 0) {
        hipLaunchKernelGGL(k_edge<0>, dim3(EB), dim3(256), 0, stream,
                           x, pos, ei, W1, b1, stats, deg, h, h_cap);
        hipLaunchKernelGGL(k_stats<0>, dim3(1024), dim3(256), 0, stream, h, stats);
        hipLaunchKernelGGL(k_bnfin, dim3(1), dim3(64), 0, stream, stats);
        hipLaunchKernelGGL(k_gate<0>, dim3(EB), dim3(256), 0, stream,
                           h, x, pos, ei, W1, b1, stats, g1, be1, Wg, bg, gate_lin, h_cap);
    } else if (mode == 1) {
        hipLaunchKernelGGL(k_edge<1>, dim3(EB), dim3(256), 0, stream,
                           x, pos, ei, W1, b1, stats, deg, h, h_cap);
        hipLaunchKernelGGL(k_stats<1>, dim3(1024), dim3(256), 0, stream, h, stats);
        hipLaunchKernelGGL(k_bnfin, dim3(1), dim3(64), 0, stream, stats);
        hipLaunchKernelGGL(k_gate<1>, dim3(EB), dim3(256), 0, stream,
                           h, x, pos, ei, W1, b1, stats, g1, be1, Wg, bg, gate_lin, h_cap);
    } else {
        hipLaunchKernelGGL(k_edge<2>, dim3(EB), dim3(256), 0, stream,
                           x, pos, ei, W1, b1, stats, deg, h, h_cap);
        hipLaunchKernelGGL(k_bnfin, dim3(1), dim3(64), 0, stream, stats);
        hipLaunchKernelGGL(k_gate<2>, dim3(EB), dim3(256), 0, stream,
                           h, x, pos, ei, W1, b1, stats, g1, be1, Wg, bg, gate_lin, h_cap);
    }

    hipLaunchKernelGGL(k_gfin, dim3(1), dim3(64), 0, stream, stats);
    hipLaunchKernelGGL(k_scan, dim3(1), dim3(1024), 0, stream, deg, offs, cursor);
    hipLaunchKernelGGL(k_fill, dim3(EB), dim3(256), 0, stream, ei, cursor, elist);

    if (mode == 0) {
        hipLaunchKernelGGL(k_aggr<0>, dim3(AB), dim3(256), 0, stream,
                           h, h_cap, gate_lin, offs, elist, ei, x, pos, b1, W1,
                           stats, g1, be1, gg, bgb, out);
    } else if (mode == 1) {
        hipLaunchKernelGGL(k_aggr<1>, dim3(AB), dim3(256), 0, stream,
                           h, h_cap, gate_lin, offs, elist, ei, x, pos, b1, W1,
                           stats, g1, be1, gg, bgb, out);
    } else {
        hipLaunchKernelGGL(k_aggr<2>, dim3(AB), dim3(256), 0, stream,
                           h, h_cap, gate_lin, offs, elist, ei, x, pos, b1, W1,
                           stats, g1, be1, gg, bgb, out);
    }
}

// Round 8
// 1583.162 us; speedup vs baseline: 1.3867x; 1.0186x over previous
//
#include <hip/hip_runtime.h>
#include <hip/hip_bf16.h>
#include <math.h>

// Problem constants (fixed by reference)
constexpr int N_NODES = 100000;
constexpr int N_EDGES = 1600000;
constexpr int IN_CH   = 61;
constexpr float BN_EPS = 1e-5f;
constexpr int NPART   = 32;   // atomic spread slots

// stats layout (floats), total 4352:
//  [0..63]    mu_h        [64..127] rs_h
//  [128] gmu  [129] grs
//  [192 ..)   part_h: slot s -> [192+s*128+c]=sum_c, [+64+c]=sumsq_c
//  [4288 ..)  part_g: slot s -> [4288+2s]=sum, [4288+2s+1]=sumsq
constexpr int S_PH = 192;
constexpr int S_PG = 192 + NPART * 128;      // 4288
constexpr int S_TOT = S_PG + NPART * 2;      // 4352

__device__ __forceinline__ float silu(float x) { return x / (1.0f + expf(-x)); }

__device__ __forceinline__ float bf2f(unsigned v) { return __uint_as_float(v << 16); }
__device__ __forceinline__ unsigned f2bf(float f) {
    unsigned u = __float_as_uint(f);
    return (u + 0x7FFFu + ((u >> 16) & 1u)) >> 16;   // RNE
}

// Full-64 matvec helper — used only by MODE 2 gate/aggr fallback paths.
__device__ __forceinline__ bool edge_gemm(
    int e, const float* __restrict__ x, const float* __restrict__ pos,
    const int* __restrict__ ei, const float* __restrict__ W1,
    const float* __restrict__ b1, float* acc, int* jd_out)
{
    int js = ei[e];
    int jd = ei[N_EDGES + e];
    *jd_out = jd;
    bool valid = ((unsigned)js < (unsigned)N_NODES) && ((unsigned)jd < (unsigned)N_NODES);
    if (!valid) {
        #pragma unroll
        for (int c = 0; c < 64; ++c) acc[c] = 0.0f;
        return false;
    }
    #pragma unroll
    for (int c = 0; c < 64; ++c) acc[c] = b1[c];

    const float* xr = x + (size_t)js * IN_CH;
    #pragma unroll 4
    for (int k = 0; k < IN_CH; ++k) {
        float fk = xr[k];
        #pragma unroll
        for (int c = 0; c < 64; ++c) acc[c] += fk * W1[k * 64 + c];
    }
    #pragma unroll
    for (int j = 0; j < 3; ++j) {
        float fk = pos[js * 3 + j] - pos[jd * 3 + j];
        #pragma unroll
        for (int c = 0; c < 64; ++c) acc[c] += fk * W1[(IN_CH + j) * 64 + c];
    }
    return true;
}

// ---- K0: init stats + deg ----
__global__ __launch_bounds__(256) void k_init(float* stats, int* deg) {
    int i = blockIdx.x * 256 + threadIdx.x;
    if (i < S_TOT) stats[i] = 0.0f;
    if (i < N_NODES) deg[i] = 0;
}

// ---- K1 v3: LDS-staged gather + per-thread 64x64 matvec in two acc[32] passes.
//      Round-7 lesson: per-lane x-row reads are uncoalesced (1.85GB TCC fetch);
//      stage rows cooperatively (lanes 0..60 = consecutive addrs, 1 load/row),
//      read f from LDS (pad 65 -> conflict-free), W1 wave-uniform -> s_load. ----
template<int MODE>
__global__ __launch_bounds__(128) void k_edge(
    const float* __restrict__ x, const float* __restrict__ pos,
    const int* __restrict__ ei, const float* __restrict__ W1,
    const float* __restrict__ b1, float* __restrict__ stats,
    int* __restrict__ deg, void* __restrict__ h, size_t h_cap)
{
    constexpr int EPB = 128;                  // edges per block
    __shared__ float fs[EPB][65];             // 33.3 KB, pad->bank-conflict-free
    __shared__ float ls[128];                 // MODE 2 partial sums

    const int tid  = threadIdx.x;
    const int wave = tid >> 6, lane = tid & 63;
    const int eb   = blockIdx.x * EPB;        // grid exact: E/128
    const int r0   = wave * 64;               // this wave's 64 rows

    // per-lane edge (also this thread's own compute edge: eb + tid)
    const int eg = eb + r0 + lane;
    int js_l = ei[eg];
    int jd_l = ei[N_EDGES + eg];
    bool valid = ((unsigned)js_l < (unsigned)N_NODES) &&
                 ((unsigned)jd_l < (unsigned)N_NODES);
    if (valid) atomicAdd(&deg[jd_l], 1);

    if constexpr (MODE == 2) {
        if (tid < 128) ls[tid] = 0.0f;
    }

    // cooperative staging: one coalesced x-row load per edge
    for (int j = 0; j < 64; ++j) {
        int js = __shfl(js_l, j);
        int jd = __shfl(jd_l, j);
        int ok = __shfl((int)valid, j);
        int r = r0 + j;
        if (lane < IN_CH) {
            fs[r][lane] = ok ? x[(size_t)js * IN_CH + lane] : 0.0f;
        } else {
            int d = lane - IN_CH;
            fs[r][lane] = ok ? (pos[js * 3 + d] - pos[jd * 3 + d]) : 0.0f;
        }
    }
    __syncthreads();

    // compute: thread tid owns edge eb+tid, feature row fs[tid][*]
    #pragma unroll 1                          // keep 2 sequential passes (VGPR!)
    for (int half = 0; half < 2; ++half) {
        const int base = half * 32;
        float acc[32];
        #pragma unroll
        for (int c = 0; c < 32; ++c) acc[c] = valid ? b1[base + c] : 0.0f;
        if (valid) {
            #pragma unroll 4
            for (int k = 0; k < 64; ++k) {
                float fk = fs[tid][k];        // LDS, conflict-free
                #pragma unroll
                for (int c = 0; c < 32; ++c)
                    acc[c] += fk * W1[k * 64 + base + c];   // uniform -> s_load
            }
        }

        if constexpr (MODE == 0) {
            if ((size_t)(eb + tid + 1) * 256 <= h_cap) {
                float4* hp = (float4*)((char*)h + (size_t)(eb + tid) * 256
                                       + (size_t)base * 4);
                #pragma unroll
                for (int i = 0; i < 8; ++i)
                    hp[i] = make_float4(acc[4*i], acc[4*i+1], acc[4*i+2], acc[4*i+3]);
            }
        } else if constexpr (MODE == 1) {
            if ((size_t)(eb + tid + 1) * 128 <= h_cap) {
                unsigned wb[16];
                #pragma unroll
                for (int i = 0; i < 16; ++i)
                    wb[i] = f2bf(acc[2*i]) | (f2bf(acc[2*i+1]) << 16);
                uint4* hp = (uint4*)((char*)h + (size_t)(eb + tid) * 128
                                     + (size_t)base * 2);
                #pragma unroll
                for (int j = 0; j < 4; ++j)
                    hp[j] = make_uint4(wb[4*j], wb[4*j+1], wb[4*j+2], wb[4*j+3]);
            }
        } else {
            #pragma unroll
            for (int c = 0; c < 32; ++c) {
                atomicAdd(&ls[base + c], acc[c]);
                atomicAdd(&ls[64 + base + c], acc[c] * acc[c]);
            }
        }
    }

    if constexpr (MODE == 2) {
        __syncthreads();
        if (tid < 128)
            atomicAdd(&stats[S_PH + (blockIdx.x & (NPART-1)) * 128 + tid], ls[tid]);
    }
}

// ---- K2: per-channel sum/sumsq streaming over h (modes 0/1 only) ----
template<int MODE>
__global__ __launch_bounds__(256) void k_stats(const void* __restrict__ h,
                                               float* __restrict__ stats)
{
    constexpr int VEC = (MODE == 0) ? 4 : 8;
    const size_t nvec = (size_t)N_EDGES * 64 / VEC;
    size_t stride = (size_t)gridDim.x * 256;
    size_t g0 = (size_t)blockIdx.x * 256 + threadIdx.x;
    int c0 = (int)((g0 * VEC) & 63);
    float sum[VEC], sq[VEC];
    #pragma unroll
    for (int j = 0; j < VEC; ++j) { sum[j] = 0.0f; sq[j] = 0.0f; }

    for (size_t v = g0; v < nvec; v += stride) {
        float vals[VEC];
        if constexpr (MODE == 0) {
            float4 t = ((const float4*)h)[v];
            vals[0] = t.x; vals[1] = t.y; vals[2] = t.z; vals[3] = t.w;
        } else {
            uint4 t = ((const uint4*)h)[v];
            vals[0] = bf2f(t.x & 0xFFFF); vals[1] = bf2f(t.x >> 16);
            vals[2] = bf2f(t.y & 0xFFFF); vals[3] = bf2f(t.y >> 16);
            vals[4] = bf2f(t.z & 0xFFFF); vals[5] = bf2f(t.z >> 16);
            vals[6] = bf2f(t.w & 0xFFFF); vals[7] = bf2f(t.w >> 16);
        }
        #pragma unroll
        for (int j = 0; j < VEC; ++j) { sum[j] += vals[j]; sq[j] += vals[j] * vals[j]; }
    }
    __shared__ float ls[128];
    if (threadIdx.x < 128) ls[threadIdx.x] = 0.0f;
    __syncthreads();
    #pragma unroll
    for (int j = 0; j < VEC; ++j) {
        atomicAdd(&ls[c0 + j], sum[j]);
        atomicAdd(&ls[64 + c0 + j], sq[j]);
    }
    __syncthreads();
    if (threadIdx.x < 128)
        atomicAdd(&stats[S_PH + (blockIdx.x & (NPART-1)) * 128 + threadIdx.x],
                  ls[threadIdx.x]);
}

// ---- K3: reduce part_h -> mu/rs ----
__global__ void k_bnfin(float* stats) {
    int c = threadIdx.x;
    if (c < 64) {
        float s = 0.0f, q = 0.0f;
        #pragma unroll
        for (int p = 0; p < NPART; ++p) {
            s += stats[S_PH + p * 128 + c];
            q += stats[S_PH + p * 128 + 64 + c];
        }
        float m = s / (float)N_EDGES;
        float v = q / (float)N_EDGES - m * m;
        stats[c] = m;
        stats[64 + c] = rsqrtf(v + BN_EPS);
    }
}

// ---- K4: gate_lin per edge + gate batch stats ----
template<int MODE>
__global__ __launch_bounds__(256) void k_gate(
    const void* __restrict__ h, const float* __restrict__ x,
    const float* __restrict__ pos, const int* __restrict__ ei,
    const float* __restrict__ W1, const float* __restrict__ b1,
    float* __restrict__ stats, const float* __restrict__ g1,
    const float* __restrict__ be1, const float* __restrict__ Wg,
    const float* __restrict__ bg, float* __restrict__ gate_lin, size_t h_cap)
{
    int e = blockIdx.x * 256 + threadIdx.x;   // grid exact
    float gl = bg[0];

    if constexpr (MODE == 2) {
        float hv[64];
        int jd;
        edge_gemm(e, x, pos, ei, W1, b1, hv, &jd);
        #pragma unroll
        for (int c = 0; c < 64; ++c) {
            float t = (hv[c] - stats[c]) * stats[64 + c] * g1[c] + be1[c];
            gl += silu(t) * Wg[c];
        }
    } else if constexpr (MODE == 0) {
        if ((size_t)(e + 1) * 256 <= h_cap) {
            const float4* hp = (const float4*)((const char*)h + (size_t)e * 256);
            #pragma unroll
            for (int i = 0; i < 16; ++i) {
                float4 t = hp[i];
                float vv[4] = {t.x, t.y, t.z, t.w};
                #pragma unroll
                for (int j = 0; j < 4; ++j) {
                    int c = 4 * i + j;
                    float tt = (vv[j] - stats[c]) * stats[64 + c] * g1[c] + be1[c];
                    gl += silu(tt) * Wg[c];
                }
            }
        }
    } else {
        if ((size_t)(e + 1) * 128 <= h_cap) {
            const uint4* hp = (const uint4*)((const char*)h + (size_t)e * 128);
            #pragma unroll
            for (int j = 0; j < 8; ++j) {
                uint4 t = hp[j];
                float vv[8];
                vv[0] = bf2f(t.x & 0xFFFF); vv[1] = bf2f(t.x >> 16);
                vv[2] = bf2f(t.y & 0xFFFF); vv[3] = bf2f(t.y >> 16);
                vv[4] = bf2f(t.z & 0xFFFF); vv[5] = bf2f(t.z >> 16);
                vv[6] = bf2f(t.w & 0xFFFF); vv[7] = bf2f(t.w >> 16);
                #pragma unroll
                for (int q = 0; q < 8; ++q) {
                    int c = 8 * j + q;
                    float tt = (vv[q] - stats[c]) * stats[64 + c] * g1[c] + be1[c];
                    gl += silu(tt) * Wg[c];
                }
            }
        }
    }
    gate_lin[e] = gl;

    float s1 = gl, s2 = gl * gl;
    #pragma unroll
    for (int off = 32; off >= 1; off >>= 1) {
        s1 += __shfl_xor(s1, off);
        s2 += __shfl_xor(s2, off);
    }
    __shared__ float red[8];
    int w = threadIdx.x >> 6, lane = threadIdx.x & 63;
    if (lane == 0) { red[w] = s1; red[4 + w] = s2; }
    __syncthreads();
    if (threadIdx.x == 0) {
        int slot = S_PG + (blockIdx.x & (NPART-1)) * 2;
        atomicAdd(&stats[slot], red[0] + red[1] + red[2] + red[3]);
        atomicAdd(&stats[slot + 1], red[4] + red[5] + red[6] + red[7]);
    }
}

// ---- K5: reduce part_g -> gmu/grs ----
__global__ void k_gfin(float* stats) {
    if (threadIdx.x == 0) {
        float s = 0.0f, q = 0.0f;
        for (int p = 0; p < NPART; ++p) {
            s += stats[S_PG + 2 * p];
            q += stats[S_PG + 2 * p + 1];
        }
        float m = s / (float)N_EDGES;
        float v = q / (float)N_EDGES - m * m;
        stats[128] = m;
        stats[129] = rsqrtf(v + BN_EPS);
    }
}

// ---- K6: single-block scan deg -> offs, cursor ----
__global__ __launch_bounds__(1024) void k_scan(const int* __restrict__ deg,
                                               int* __restrict__ offs,
                                               int* __restrict__ cursor)
{
    __shared__ int ps[1024];
    int t = threadIdx.x;
    const int CH = (N_NODES + 1023) / 1024;
    int lo = t * CH, hi = lo + CH;
    if (hi > N_NODES) hi = N_NODES;
    if (lo > N_NODES) lo = N_NODES;
    int s = 0;
    for (int i = lo; i < hi; ++i) s += deg[i];
    ps[t] = s;
    __syncthreads();
    for (int off = 1; off < 1024; off <<= 1) {
        int v = (t >= off) ? ps[t - off] : 0;
        __syncthreads();
        ps[t] += v;
        __syncthreads();
    }
    int run = (t == 0) ? 0 : ps[t - 1];
    for (int i = lo; i < hi; ++i) {
        offs[i] = run;
        cursor[i] = run;
        run += deg[i];
    }
    if (t == 1023) offs[N_NODES] = ps[1023];
}

// ---- K7: CSR fill ----
__global__ __launch_bounds__(256) void k_fill(const int* __restrict__ ei,
                                              int* __restrict__ cursor,
                                              int* __restrict__ elist)
{
    int e = blockIdx.x * 256 + threadIdx.x;
    int js = ei[e];
    int d = ei[N_EDGES + e];
    if ((unsigned)js >= (unsigned)N_NODES || (unsigned)d >= (unsigned)N_NODES) return;
    int p = atomicAdd(&cursor[d], 1);
    if ((unsigned)p < (unsigned)N_EDGES) elist[p] = e;
}

// ---- K8: wave per node, lane = channel; 1-deep software pipeline (modes 0/1) ----
template<int MODE>
__device__ __forceinline__ void aggr_body(
    const void* __restrict__ h, size_t h_cap, const float* __restrict__ gate_lin,
    const int* __restrict__ offs, const int* __restrict__ elist,
    const int* __restrict__ ei, const float* __restrict__ x,
    const float* __restrict__ pos, const float* __restrict__ b1,
    const float* W1s, const float* __restrict__ stats,
    const float* __restrict__ g1, const float* __restrict__ be1,
    const float* __restrict__ gg, const float* __restrict__ bgb,
    float* __restrict__ out)
{
    int wid = (blockIdx.x * 256 + threadIdx.x) >> 6;
    int lane = threadIdx.x & 63;
    if (wid >= N_NODES) return;

    float mu = stats[lane], rs = stats[64 + lane];
    float gmu = stats[128], grs = stats[129];
    float ga = g1[lane], bb = be1[lane];
    float gga = gg[0], gbb = bgb[0];

    int lo = offs[wid], hi = offs[wid + 1];
    float accv = 0.0f, wsum = 0.0f;

    if constexpr (MODE == 2) {
        float b1v = b1[lane];
        float pim = (lane >= IN_CH) ? pos[wid * 3 + (lane - IN_CH)] : 0.0f;
        for (int i = lo; i < hi; ++i) {
            int e = elist[i];
            float gl = gate_lin[e];
            float tg = (gl - gmu) * grs * gga + gbb;
            float w = expf(silu(tg));
            int js = ei[e];
            if ((unsigned)js >= (unsigned)N_NODES) continue;
            float fl = (lane < IN_CH) ? x[(size_t)js * IN_CH + lane]
                                      : pos[js * 3 + (lane - IN_CH)] - pim;
            float a = b1v;
            #pragma unroll
            for (int k = 0; k < 64; ++k) a += __shfl(fl, k) * W1s[k * 64 + lane];
            float tn = (a - mu) * rs * ga + bb;
            accv += w * silu(tn);
            wsum += w;
        }
    } else {
        auto load_h = [&](int e) -> float {
            if constexpr (MODE == 0) {
                if ((size_t)(e + 1) * 256 > h_cap) return 0.0f;
                return ((const float*)h)[(size_t)e * 64 + lane];
            } else {
                if ((size_t)(e + 1) * 128 > h_cap) return 0.0f;
                return bf2f(((const unsigned short*)h)[(size_t)e * 64 + lane]);
            }
        };
        if (lo < hi) {
            int e = elist[lo];
            float gl = gate_lin[e];
            float hval = load_h(e);
            for (int i = lo; i < hi; ++i) {
                int en = 0; float gln = 0.0f, hn = 0.0f;
                if (i + 1 < hi) {            // prefetch next edge while computing
                    en = elist[i + 1];
                    gln = gate_lin[en];
                    hn = load_h(en);
                }
                float tg = (gl - gmu) * grs * gga + gbb;
                float w = expf(silu(tg));    // BN-standardized: no max-shift needed
                float tn = (hval - mu) * rs * ga + bb;
                accv += w * silu(tn);
                wsum += w;
                e = en; gl = gln; hval = hn;
            }
        }
    }
    out[(size_t)wid * 64 + lane] = accv / (wsum + 1e-16f);
}

template<int MODE>
__global__ __launch_bounds__(256) void k_aggr(
    const void* __restrict__ h, size_t h_cap, const float* __restrict__ gate_lin,
    const int* __restrict__ offs, const int* __restrict__ elist,
    const int* __restrict__ ei, const float* __restrict__ x,
    const float* __restrict__ pos, const float* __restrict__ b1,
    const float* __restrict__ W1, const float* __restrict__ stats,
    const float* __restrict__ g1, const float* __restrict__ be1,
    const float* __restrict__ gg, const float* __restrict__ bgb,
    float* __restrict__ out)
{
    if constexpr (MODE == 2) {
        __shared__ float W1s[4096];
        for (int i = threadIdx.x; i < 4096; i += 256) W1s[i] = W1[i];
        __syncthreads();
        aggr_body<2>(h, h_cap, gate_lin, offs, elist, ei, x, pos, b1, W1s,
                     stats, g1, be1, gg, bgb, out);
    } else {
        aggr_body<MODE>(h, h_cap, gate_lin, offs, elist, ei, x, pos, b1, nullptr,
                        stats, g1, be1, gg, bgb, out);
    }
}

extern "C" void kernel_launch(void* const* d_in, const int* in_sizes, int n_in,
                              void* d_out, int out_size, void* d_ws, size_t ws_size,
                              hipStream_t stream)
{
    const float* x   = (const float*)d_in[0];
    const float* pos = (const float*)d_in[1];
    const int*   ei  = (const int*)d_in[2];
    const float* W1  = (const float*)d_in[3];
    const float* b1  = (const float*)d_in[4];
    const float* g1  = (const float*)d_in[5];
    const float* be1 = (const float*)d_in[6];
    const float* Wg  = (const float*)d_in[7];
    const float* bg  = (const float*)d_in[8];
    const float* gg  = (const float*)d_in[9];
    const float* bgb = (const float*)d_in[10];
    float* out = (float*)d_out;

    // --- adaptive ws layout: small structures first, h (if it fits) last ---
    char* base = (char*)d_ws;
    size_t off = 0;
    auto alloc = [&](size_t bytes) {
        size_t o = off;
        off = (off + bytes + 255) & ~(size_t)255;
        return o;
    };
    float* stats    = (float*)(base + alloc(S_TOT * 4));
    int*   deg      = (int*)(base + alloc((size_t)N_NODES * 4));
    int*   offs     = (int*)(base + alloc((size_t)(N_NODES + 1) * 4));
    int*   cursor   = (int*)(base + alloc((size_t)N_NODES * 4));
    int*   elist    = (int*)(base + alloc((size_t)N_EDGES * 4));
    float* gate_lin = (float*)(base + alloc((size_t)N_EDGES * 4));
    if (ws_size < off) return;
    void*  h     = (void*)(base + off);
    size_t h_cap = ws_size - off;

    const int mode = (h_cap >= (size_t)N_EDGES * 256) ? 0
                   : (h_cap >= (size_t)N_EDGES * 128) ? 1 : 2;

    const int EB  = N_EDGES / 256;           // 6250 exact
    const int EB2 = N_EDGES / 128;           // 12500 exact (k_edge v3)
    const int NB  = (N_NODES + 255) / 256;   // 391
    const int AB  = (N_NODES + 3) / 4;       // 25001

    hipLaunchKernelGGL(k_init, dim3(NB), dim3(256), 0, stream, stats, deg);

    if (mode == 0) {
        hipLaunchKernelGGL(k_edge<0>, dim3(EB2), dim3(128), 0, stream,
                           x, pos, ei, W1, b1, stats, deg, h, h_cap);
        hipLaunchKernelGGL(k_stats<0>, dim3(1024), dim3(256), 0, stream, h, stats);
        hipLaunchKernelGGL(k_bnfin, dim3(1), dim3(64), 0, stream, stats);
        hipLaunchKernelGGL(k_gate<0>, dim3(EB), dim3(256), 0, stream,
                           h, x, pos, ei, W1, b1, stats, g1, be1, Wg, bg, gate_lin, h_cap);
    } else if (mode == 1) {
        hipLaunchKernelGGL(k_edge<1>, dim3(EB2), dim3(128), 0, stream,
                           x, pos, ei, W1, b1, stats, deg, h, h_cap);
        hipLaunchKernelGGL(k_stats<1>, dim3(1024), dim3(256), 0, stream, h, stats);
        hipLaunchKernelGGL(k_bnfin, dim3(1), dim3(64), 0, stream, stats);
        hipLaunchKernelGGL(k_gate<1>, dim3(EB), dim3(256), 0, stream,
                           h, x, pos, ei, W1, b1, stats, g1, be1, Wg, bg, gate_lin, h_cap);
    } else {
        hipLaunchKernelGGL(k_edge<2>, dim3(EB2), dim3(128), 0, stream,
                           x, pos, ei, W1, b1, stats, deg, h, h_cap);
        hipLaunchKernelGGL(k_bnfin, dim3(1), dim3(64), 0, stream, stats);
        hipLaunchKernelGGL(k_gate<2>, dim3(EB), dim3(256), 0, stream,
                           h, x, pos, ei, W1, b1, stats, g1, be1, Wg, bg, gate_lin, h_cap);
    }

    hipLaunchKernelGGL(k_gfin, dim3(1), dim3(64), 0, stream, stats);
    hipLaunchKernelGGL(k_scan, dim3(1), dim3(1024), 0, stream, deg, offs, cursor);
    hipLaunchKernelGGL(k_fill, dim3(EB), dim3(256), 0, stream, ei, cursor, elist);

    if (mode == 0) {
        hipLaunchKernelGGL(k_aggr<0>, dim3(AB), dim3(256), 0, stream,
                           h, h_cap, gate_lin, offs, elist, ei, x, pos, b1, W1,
                           stats, g1, be1, gg, bgb, out);
    } else if (mode == 1) {
        hipLaunchKernelGGL(k_aggr<1>, dim3(AB), dim3(256), 0, stream,
                           h, h_cap, gate_lin, offs, elist, ei, x, pos, b1, W1,
                           stats, g1, be1, gg, bgb, out);
    } else {
        hipLaunchKernelGGL(k_aggr<2>, dim3(AB), dim3(256), 0, stream,
                           h, h_cap, gate_lin, offs, elist, ei, x, pos, b1, W1,
                           stats, g1, be1, gg, bgb, out);
    }
}

// Round 9
// 1356.592 us; speedup vs baseline: 1.6183x; 1.1670x over previous
//
#include <hip/hip_runtime.h>
#include <hip/hip_bf16.h>
#include <math.h>

// Problem constants (fixed by reference)
constexpr int N_NODES = 100000;
constexpr int N_EDGES = 1600000;
constexpr int IN_CH   = 61;
constexpr float BN_EPS = 1e-5f;
constexpr int NPART   = 32;   // atomic spread slots

// stats layout (floats), total 4352:
//  [0..63] mu_h   [64..127] rs_h   [128] gmu [129] grs
//  [192..) part_h: slot s -> [192+s*128+c]=sum_c, [+64+c]=sumsq_c
//  [4288..) part_g: slot s -> [4288+2s]=sum, [+1]=sumsq
constexpr int S_PH = 192;
constexpr int S_PG = 192 + NPART * 128;      // 4288
constexpr int S_TOT = S_PG + NPART * 2;      // 4352

typedef float f32x4 __attribute__((ext_vector_type(4)));
typedef short s16x8 __attribute__((ext_vector_type(8)));

__device__ __forceinline__ float silu(float x) { return x / (1.0f + expf(-x)); }

__device__ __forceinline__ float bf2f(unsigned v) { return __uint_as_float(v << 16); }
__device__ __forceinline__ unsigned f2bf(float f) {
    unsigned u = __float_as_uint(f);
    return (u + 0x7FFFu + ((u >> 16) & 1u)) >> 16;   // RNE
}

// Full-64 matvec helper — used only by MODE 2 / mode 0 legacy paths.
__device__ __forceinline__ bool edge_gemm(
    int e, const float* __restrict__ x, const float* __restrict__ pos,
    const int* __restrict__ ei, const float* __restrict__ W1,
    const float* __restrict__ b1, float* acc, int* jd_out)
{
    int js = ei[e];
    int jd = ei[N_EDGES + e];
    *jd_out = jd;
    bool valid = ((unsigned)js < (unsigned)N_NODES) && ((unsigned)jd < (unsigned)N_NODES);
    if (!valid) {
        #pragma unroll
        for (int c = 0; c < 64; ++c) acc[c] = 0.0f;
        return false;
    }
    #pragma unroll
    for (int c = 0; c < 64; ++c) acc[c] = b1[c];
    const float* xr = x + (size_t)js * IN_CH;
    #pragma unroll 4
    for (int k = 0; k < IN_CH; ++k) {
        float fk = xr[k];
        #pragma unroll
        for (int c = 0; c < 64; ++c) acc[c] += fk * W1[k * 64 + c];
    }
    #pragma unroll
    for (int j = 0; j < 3; ++j) {
        float fk = pos[js * 3 + j] - pos[jd * 3 + j];
        #pragma unroll
        for (int c = 0; c < 64; ++c) acc[c] += fk * W1[(IN_CH + j) * 64 + c];
    }
    return true;
}

// ---- K0: init stats + deg ----
__global__ __launch_bounds__(256) void k_init(float* stats, int* deg) {
    int i = blockIdx.x * 256 + threadIdx.x;
    if (i < S_TOT) stats[i] = 0.0f;
    if (i < N_NODES) deg[i] = 0;
}

// ---- K1 v4 (mode 1): MFMA edge GEMM, 64 edges/block, 4 waves.
//  f and W1 staged in LDS as bf16 hi+lo; bf16x3 MFMA (AhBh+AhBl+AlBh) ~ fp32.
//  Fragment maps (guide-verified): A row=lane&15,k=(lane>>4)*8+j;
//  B col=lane&15,same k; C col=lane&15,row=(lane>>4)*4+reg.
//  Epilogue: bf16 h via LDS tile (coalesced dump) + fused per-channel stats. ----
__global__ __launch_bounds__(256) void k_edge_mfma(
    const float* __restrict__ x, const float* __restrict__ pos,
    const int* __restrict__ ei, const float* __restrict__ W1,
    const float* __restrict__ b1, float* __restrict__ stats,
    int* __restrict__ deg, void* __restrict__ h, size_t h_cap)
{
    __shared__ __align__(16) short fsh[64][72];   // f hi (bf16), pad 72 -> 144B rows
    __shared__ __align__(16) short fsl[64][72];   // f lo
    __shared__ __align__(16) short wth[64][72];   // W1^T hi: [ch][k]
    __shared__ __align__(16) short wtl[64][72];   // W1^T lo
    __shared__ __align__(16) short hs[64][64];    // output tile (bf16)
    __shared__ float lsum[128];                   // fused stats partials

    const int tid  = threadIdx.x;
    const int w    = tid >> 6, lane = tid & 63;
    const int e0   = blockIdx.x * 64;             // grid exact: E/64

    if (tid < 128) lsum[tid] = 0.0f;

    // --- stage W1^T as bf16 hi/lo (coalesced global read; 16KB, L2-hot) ---
    #pragma unroll 4
    for (int i = tid; i < 4096; i += 256) {
        int k = i >> 6, c = i & 63;
        float v = W1[i];
        unsigned hi = f2bf(v);
        unsigned lo = f2bf(v - bf2f(hi));
        wth[c][k] = (short)hi;
        wtl[c][k] = (short)lo;
    }

    // --- indices + deg histogram (16 edges per wave) ---
    int js_l = 0, jd_l = 0;
    if (lane < 16) {
        int e = e0 + w * 16 + lane;
        js_l = ei[e];
        jd_l = ei[N_EDGES + e];
        if ((unsigned)js_l >= (unsigned)N_NODES) js_l = 0;
        if ((unsigned)jd_l >= (unsigned)N_NODES) jd_l = 0;
        atomicAdd(&deg[jd_l], 1);
    }

    // --- stage f rows (wave w -> rows w*16..w*16+15), coalesced per row ---
    #pragma unroll 4
    for (int j = 0; j < 16; ++j) {
        int js = __shfl(js_l, j);
        int jd = __shfl(jd_l, j);
        int r  = w * 16 + j;
        float v;
        if (lane < IN_CH) v = x[(size_t)js * IN_CH + lane];
        else              v = pos[js * 3 + (lane - IN_CH)] - pos[jd * 3 + (lane - IN_CH)];
        unsigned hi = f2bf(v);
        unsigned lo = f2bf(v - bf2f(hi));
        fsh[r][lane] = (short)hi;
        fsl[r][lane] = (short)lo;
    }
    __syncthreads();

    // --- MFMA: wave w computes rows w*16..+15 x all 64 channels ---
    const int r = lane & 15, g = lane >> 4;
    const int arow = w * 16 + r;
    s16x8 ah0 = *(const s16x8*)&fsh[arow][g * 8];
    s16x8 ah1 = *(const s16x8*)&fsh[arow][32 + g * 8];
    s16x8 al0 = *(const s16x8*)&fsl[arow][g * 8];
    s16x8 al1 = *(const s16x8*)&fsl[arow][32 + g * 8];

    #pragma unroll
    for (int ct = 0; ct < 4; ++ct) {
        int c = ct * 16 + r;
        s16x8 bh0 = *(const s16x8*)&wth[c][g * 8];
        s16x8 bh1 = *(const s16x8*)&wth[c][32 + g * 8];
        s16x8 bl0 = *(const s16x8*)&wtl[c][g * 8];
        s16x8 bl1 = *(const s16x8*)&wtl[c][32 + g * 8];
        f32x4 acc = {0.0f, 0.0f, 0.0f, 0.0f};
        acc = __builtin_amdgcn_mfma_f32_16x16x32_bf16(al0, bh0, acc, 0, 0, 0);
        acc = __builtin_amdgcn_mfma_f32_16x16x32_bf16(al1, bh1, acc, 0, 0, 0);
        acc = __builtin_amdgcn_mfma_f32_16x16x32_bf16(ah0, bl0, acc, 0, 0, 0);
        acc = __builtin_amdgcn_mfma_f32_16x16x32_bf16(ah1, bl1, acc, 0, 0, 0);
        acc = __builtin_amdgcn_mfma_f32_16x16x32_bf16(ah0, bh0, acc, 0, 0, 0);
        acc = __builtin_amdgcn_mfma_f32_16x16x32_bf16(ah1, bh1, acc, 0, 0, 0);
        float bias = b1[c];
        #pragma unroll
        for (int i = 0; i < 4; ++i)
            hs[w * 16 + g * 4 + i][c] = (short)f2bf(acc[i] + bias);
    }
    __syncthreads();

    // --- coalesced bf16 h dump (8KB) ---
    if ((size_t)(e0 + 64) * 128 <= h_cap) {
        const uint4* src = (const uint4*)&hs[0][0];
        uint4* dst = (uint4*)((char*)h + (size_t)e0 * 128);
        #pragma unroll
        for (int i = tid; i < 512; i += 256) dst[i] = src[i];
    }

    // --- fused per-channel stats (from bf16-rounded h, same as k_stats<1>) ---
    {
        int col = tid & 63, rq = tid >> 6;
        float s = 0.0f, q = 0.0f;
        #pragma unroll
        for (int rr = 0; rr < 16; ++rr) {
            float v = bf2f((unsigned short)hs[rq * 16 + rr][col]);
            s += v; q += v * v;
        }
        atomicAdd(&lsum[col], s);
        atomicAdd(&lsum[64 + col], q);
    }
    __syncthreads();
    if (tid < 128)
        atomicAdd(&stats[S_PH + (blockIdx.x & (NPART - 1)) * 128 + tid], lsum[tid]);
}

// ---- K1 legacy (modes 0/2): LDS-staged scalar path ----
template<int MODE>
__global__ __launch_bounds__(128) void k_edge(
    const float* __restrict__ x, const float* __restrict__ pos,
    const int* __restrict__ ei, const float* __restrict__ W1,
    const float* __restrict__ b1, float* __restrict__ stats,
    int* __restrict__ deg, void* __restrict__ h, size_t h_cap)
{
    constexpr int EPB = 128;
    __shared__ float fs[EPB][65];
    __shared__ float ls[128];

    const int tid  = threadIdx.x;
    const int wave = tid >> 6, lane = tid & 63;
    const int eb   = blockIdx.x * EPB;
    const int r0   = wave * 64;

    const int eg = eb + r0 + lane;
    int js_l = ei[eg];
    int jd_l = ei[N_EDGES + eg];
    bool valid = ((unsigned)js_l < (unsigned)N_NODES) &&
                 ((unsigned)jd_l < (unsigned)N_NODES);
    if (valid) atomicAdd(&deg[jd_l], 1);

    if constexpr (MODE == 2) {
        if (tid < 128) ls[tid] = 0.0f;
    }

    for (int j = 0; j < 64; ++j) {
        int js = __shfl(js_l, j);
        int jd = __shfl(jd_l, j);
        int ok = __shfl((int)valid, j);
        int r = r0 + j;
        if (lane < IN_CH) {
            fs[r][lane] = ok ? x[(size_t)js * IN_CH + lane] : 0.0f;
        } else {
            int d = lane - IN_CH;
            fs[r][lane] = ok ? (pos[js * 3 + d] - pos[jd * 3 + d]) : 0.0f;
        }
    }
    __syncthreads();

    #pragma unroll 1
    for (int half = 0; half < 2; ++half) {
        const int base = half * 32;
        float acc[32];
        #pragma unroll
        for (int c = 0; c < 32; ++c) acc[c] = valid ? b1[base + c] : 0.0f;
        if (valid) {
            #pragma unroll 4
            for (int k = 0; k < 64; ++k) {
                float fk = fs[tid][k];
                #pragma unroll
                for (int c = 0; c < 32; ++c)
                    acc[c] += fk * W1[k * 64 + base + c];
            }
        }
        if constexpr (MODE == 0) {
            if ((size_t)(eb + tid + 1) * 256 <= h_cap) {
                float4* hp = (float4*)((char*)h + (size_t)(eb + tid) * 256
                                       + (size_t)base * 4);
                #pragma unroll
                for (int i = 0; i < 8; ++i)
                    hp[i] = make_float4(acc[4*i], acc[4*i+1], acc[4*i+2], acc[4*i+3]);
            }
        } else {
            #pragma unroll
            for (int c = 0; c < 32; ++c) {
                atomicAdd(&ls[base + c], acc[c]);
                atomicAdd(&ls[64 + base + c], acc[c] * acc[c]);
            }
        }
    }

    if constexpr (MODE == 2) {
        __syncthreads();
        if (tid < 128)
            atomicAdd(&stats[S_PH + (blockIdx.x & (NPART-1)) * 128 + tid], ls[tid]);
    }
}

// ---- K2: per-channel sum/sumsq streaming over h (mode 0 only now) ----
template<int MODE>
__global__ __launch_bounds__(256) void k_stats(const void* __restrict__ h,
                                               float* __restrict__ stats)
{
    constexpr int VEC = (MODE == 0) ? 4 : 8;
    const size_t nvec = (size_t)N_EDGES * 64 / VEC;
    size_t stride = (size_t)gridDim.x * 256;
    size_t g0 = (size_t)blockIdx.x * 256 + threadIdx.x;
    int c0 = (int)((g0 * VEC) & 63);
    float sum[VEC], sq[VEC];
    #pragma unroll
    for (int j = 0; j < VEC; ++j) { sum[j] = 0.0f; sq[j] = 0.0f; }

    for (size_t v = g0; v < nvec; v += stride) {
        float vals[VEC];
        if constexpr (MODE == 0) {
            float4 t = ((const float4*)h)[v];
            vals[0] = t.x; vals[1] = t.y; vals[2] = t.z; vals[3] = t.w;
        } else {
            uint4 t = ((const uint4*)h)[v];
            vals[0] = bf2f(t.x & 0xFFFF); vals[1] = bf2f(t.x >> 16);
            vals[2] = bf2f(t.y & 0xFFFF); vals[3] = bf2f(t.y >> 16);
            vals[4] = bf2f(t.z & 0xFFFF); vals[5] = bf2f(t.z >> 16);
            vals[6] = bf2f(t.w & 0xFFFF); vals[7] = bf2f(t.w >> 16);
        }
        #pragma unroll
        for (int j = 0; j < VEC; ++j) { sum[j] += vals[j]; sq[j] += vals[j] * vals[j]; }
    }
    __shared__ float ls[128];
    if (threadIdx.x < 128) ls[threadIdx.x] = 0.0f;
    __syncthreads();
    #pragma unroll
    for (int j = 0; j < VEC; ++j) {
        atomicAdd(&ls[c0 + j], sum[j]);
        atomicAdd(&ls[64 + c0 + j], sq[j]);
    }
    __syncthreads();
    if (threadIdx.x < 128)
        atomicAdd(&stats[S_PH + (blockIdx.x & (NPART-1)) * 128 + threadIdx.x],
                  ls[threadIdx.x]);
}

// ---- K3: reduce part_h -> mu/rs ----
__global__ void k_bnfin(float* stats) {
    int c = threadIdx.x;
    if (c < 64) {
        float s = 0.0f, q = 0.0f;
        #pragma unroll
        for (int p = 0; p < NPART; ++p) {
            s += stats[S_PH + p * 128 + c];
            q += stats[S_PH + p * 128 + 64 + c];
        }
        float m = s / (float)N_EDGES;
        float v = q / (float)N_EDGES - m * m;
        stats[c] = m;
        stats[64 + c] = rsqrtf(v + BN_EPS);
    }
}

// ---- K4: gate_lin per edge + gate batch stats ----
template<int MODE>
__global__ __launch_bounds__(256) void k_gate(
    const void* __restrict__ h, const float* __restrict__ x,
    const float* __restrict__ pos, const int* __restrict__ ei,
    const float* __restrict__ W1, const float* __restrict__ b1,
    float* __restrict__ stats, const float* __restrict__ g1,
    const float* __restrict__ be1, const float* __restrict__ Wg,
    const float* __restrict__ bg, float* __restrict__ gate_lin, size_t h_cap)
{
    int e = blockIdx.x * 256 + threadIdx.x;
    float gl = bg[0];

    if constexpr (MODE == 2) {
        float hv[64];
        int jd;
        edge_gemm(e, x, pos, ei, W1, b1, hv, &jd);
        #pragma unroll
        for (int c = 0; c < 64; ++c) {
            float t = (hv[c] - stats[c]) * stats[64 + c] * g1[c] + be1[c];
            gl += silu(t) * Wg[c];
        }
    } else if constexpr (MODE == 0) {
        if ((size_t)(e + 1) * 256 <= h_cap) {
            const float4* hp = (const float4*)((const char*)h + (size_t)e * 256);
            #pragma unroll
            for (int i = 0; i < 16; ++i) {
                float4 t = hp[i];
                float vv[4] = {t.x, t.y, t.z, t.w};
                #pragma unroll
                for (int j = 0; j < 4; ++j) {
                    int c = 4 * i + j;
                    float tt = (vv[j] - stats[c]) * stats[64 + c] * g1[c] + be1[c];
                    gl += silu(tt) * Wg[c];
                }
            }
        }
    } else {
        if ((size_t)(e + 1) * 128 <= h_cap) {
            const uint4* hp = (const uint4*)((const char*)h + (size_t)e * 128);
            #pragma unroll
            for (int j = 0; j < 8; ++j) {
                uint4 t = hp[j];
                float vv[8];
                vv[0] = bf2f(t.x & 0xFFFF); vv[1] = bf2f(t.x >> 16);
                vv[2] = bf2f(t.y & 0xFFFF); vv[3] = bf2f(t.y >> 16);
                vv[4] = bf2f(t.z & 0xFFFF); vv[5] = bf2f(t.z >> 16);
                vv[6] = bf2f(t.w & 0xFFFF); vv[7] = bf2f(t.w >> 16);
                #pragma unroll
                for (int q = 0; q < 8; ++q) {
                    int c = 8 * j + q;
                    float tt = (vv[q] - stats[c]) * stats[64 + c] * g1[c] + be1[c];
                    gl += silu(tt) * Wg[c];
                }
            }
        }
    }
    gate_lin[e] = gl;

    float s1 = gl, s2 = gl * gl;
    #pragma unroll
    for (int off = 32; off >= 1; off >>= 1) {
        s1 += __shfl_xor(s1, off);
        s2 += __shfl_xor(s2, off);
    }
    __shared__ float red[8];
    int w = threadIdx.x >> 6, lane = threadIdx.x & 63;
    if (lane == 0) { red[w] = s1; red[4 + w] = s2; }
    __syncthreads();
    if (threadIdx.x == 0) {
        int slot = S_PG + (blockIdx.x & (NPART-1)) * 2;
        atomicAdd(&stats[slot], red[0] + red[1] + red[2] + red[3]);
        atomicAdd(&stats[slot + 1], red[4] + red[5] + red[6] + red[7]);
    }
}

// ---- K5: reduce part_g -> gmu/grs ----
__global__ void k_gfin(float* stats) {
    if (threadIdx.x == 0) {
        float s = 0.0f, q = 0.0f;
        for (int p = 0; p < NPART; ++p) {
            s += stats[S_PG + 2 * p];
            q += stats[S_PG + 2 * p + 1];
        }
        float m = s / (float)N_EDGES;
        float v = q / (float)N_EDGES - m * m;
        stats[128] = m;
        stats[129] = rsqrtf(v + BN_EPS);
    }
}

// ---- K6: single-block scan deg -> offs, cursor ----
__global__ __launch_bounds__(1024) void k_scan(const int* __restrict__ deg,
                                               int* __restrict__ offs,
                                               int* __restrict__ cursor)
{
    __shared__ int ps[1024];
    int t = threadIdx.x;
    const int CH = (N_NODES + 1023) / 1024;
    int lo = t * CH, hi = lo + CH;
    if (hi > N_NODES) hi = N_NODES;
    if (lo > N_NODES) lo = N_NODES;
    int s = 0;
    for (int i = lo; i < hi; ++i) s += deg[i];
    ps[t] = s;
    __syncthreads();
    for (int off = 1; off < 1024; off <<= 1) {
        int v = (t >= off) ? ps[t - off] : 0;
        __syncthreads();
        ps[t] += v;
        __syncthreads();
    }
    int run = (t == 0) ? 0 : ps[t - 1];
    for (int i = lo; i < hi; ++i) {
        offs[i] = run;
        cursor[i] = run;
        run += deg[i];
    }
    if (t == 1023) offs[N_NODES] = ps[1023];
}

// ---- K7: CSR fill ----
__global__ __launch_bounds__(256) void k_fill(const int* __restrict__ ei,
                                              int* __restrict__ cursor,
                                              int* __restrict__ elist)
{
    int e = blockIdx.x * 256 + threadIdx.x;
    int js = ei[e];
    int d = ei[N_EDGES + e];
    if ((unsigned)js >= (unsigned)N_NODES || (unsigned)d >= (unsigned)N_NODES) return;
    int p = atomicAdd(&cursor[d], 1);
    if ((unsigned)p < (unsigned)N_EDGES) elist[p] = e;
}

// ---- K8: wave per node, lane = channel; 1-deep software pipeline (modes 0/1) ----
template<int MODE>
__device__ __forceinline__ void aggr_body(
    const void* __restrict__ h, size_t h_cap, const float* __restrict__ gate_lin,
    const int* __restrict__ offs, const int* __restrict__ elist,
    const int* __restrict__ ei, const float* __restrict__ x,
    const float* __restrict__ pos, const float* __restrict__ b1,
    const float* W1s, const float* __restrict__ stats,
    const float* __restrict__ g1, const float* __restrict__ be1,
    const float* __restrict__ gg, const float* __restrict__ bgb,
    float* __restrict__ out)
{
    int wid = (blockIdx.x * 256 + threadIdx.x) >> 6;
    int lane = threadIdx.x & 63;
    if (wid >= N_NODES) return;

    float mu = stats[lane], rs = stats[64 + lane];
    float gmu = stats[128], grs = stats[129];
    float ga = g1[lane], bb = be1[lane];
    float gga = gg[0], gbb = bgb[0];

    int lo = offs[wid], hi = offs[wid + 1];
    float accv = 0.0f, wsum = 0.0f;

    if constexpr (MODE == 2) {
        float b1v = b1[lane];
        float pim = (lane >= IN_CH) ? pos[wid * 3 + (lane - IN_CH)] : 0.0f;
        for (int i = lo; i < hi; ++i) {
            int e = elist[i];
            float gl = gate_lin[e];
            float tg = (gl - gmu) * grs * gga + gbb;
            float w = expf(silu(tg));
            int js = ei[e];
            if ((unsigned)js >= (unsigned)N_NODES) continue;
            float fl = (lane < IN_CH) ? x[(size_t)js * IN_CH + lane]
                                      : pos[js * 3 + (lane - IN_CH)] - pim;
            float a = b1v;
            #pragma unroll
            for (int k = 0; k < 64; ++k) a += __shfl(fl, k) * W1s[k * 64 + lane];
            float tn = (a - mu) * rs * ga + bb;
            accv += w * silu(tn);
            wsum += w;
        }
    } else {
        auto load_h = [&](int e) -> float {
            if constexpr (MODE == 0) {
                if ((size_t)(e + 1) * 256 > h_cap) return 0.0f;
                return ((const float*)h)[(size_t)e * 64 + lane];
            } else {
                if ((size_t)(e + 1) * 128 > h_cap) return 0.0f;
                return bf2f(((const unsigned short*)h)[(size_t)e * 64 + lane]);
            }
        };
        if (lo < hi) {
            int e = elist[lo];
            float gl = gate_lin[e];
            float hval = load_h(e);
            for (int i = lo; i < hi; ++i) {
                int en = 0; float gln = 0.0f, hn = 0.0f;
                if (i + 1 < hi) {
                    en = elist[i + 1];
                    gln = gate_lin[en];
                    hn = load_h(en);
                }
                float tg = (gl - gmu) * grs * gga + gbb;
                float w = expf(silu(tg));
                float tn = (hval - mu) * rs * ga + bb;
                accv += w * silu(tn);
                wsum += w;
                e = en; gl = gln; hval = hn;
            }
        }
    }
    out[(size_t)wid * 64 + lane] = accv / (wsum + 1e-16f);
}

template<int MODE>
__global__ __launch_bounds__(256) void k_aggr(
    const void* __restrict__ h, size_t h_cap, const float* __restrict__ gate_lin,
    const int* __restrict__ offs, const int* __restrict__ elist,
    const int* __restrict__ ei, const float* __restrict__ x,
    const float* __restrict__ pos, const float* __restrict__ b1,
    const float* __restrict__ W1, const float* __restrict__ stats,
    const float* __restrict__ g1, const float* __restrict__ be1,
    const float* __restrict__ gg, const float* __restrict__ bgb,
    float* __restrict__ out)
{
    if constexpr (MODE == 2) {
        __shared__ float W1s[4096];
        for (int i = threadIdx.x; i < 4096; i += 256) W1s[i] = W1[i];
        __syncthreads();
        aggr_body<2>(h, h_cap, gate_lin, offs, elist, ei, x, pos, b1, W1s,
                     stats, g1, be1, gg, bgb, out);
    } else {
        aggr_body<MODE>(h, h_cap, gate_lin, offs, elist, ei, x, pos, b1, nullptr,
                        stats, g1, be1, gg, bgb, out);
    }
}

extern "C" void kernel_launch(void* const* d_in, const int* in_sizes, int n_in,
                              void* d_out, int out_size, void* d_ws, size_t ws_size,
                              hipStream_t stream)
{
    const float* x   = (const float*)d_in[0];
    const float* pos = (const float*)d_in[1];
    const int*   ei  = (const int*)d_in[2];
    const float* W1  = (const float*)d_in[3];
    const float* b1  = (const float*)d_in[4];
    const float* g1  = (const float*)d_in[5];
    const float* be1 = (const float*)d_in[6];
    const float* Wg  = (const float*)d_in[7];
    const float* bg  = (const float*)d_in[8];
    const float* gg  = (const float*)d_in[9];
    const float* bgb = (const float*)d_in[10];
    float* out = (float*)d_out;

    char* base = (char*)d_ws;
    size_t off = 0;
    auto alloc = [&](size_t bytes) {
        size_t o = off;
        off = (off + bytes + 255) & ~(size_t)255;
        return o;
    };
    float* stats    = (float*)(base + alloc(S_TOT * 4));
    int*   deg      = (int*)(base + alloc((size_t)N_NODES * 4));
    int*   offs     = (int*)(base + alloc((size_t)(N_NODES + 1) * 4));
    int*   cursor   = (int*)(base + alloc((size_t)N_NODES * 4));
    int*   elist    = (int*)(base + alloc((size_t)N_EDGES * 4));
    float* gate_lin = (float*)(base + alloc((size_t)N_EDGES * 4));
    if (ws_size < off) return;
    void*  h     = (void*)(base + off);
    size_t h_cap = ws_size - off;

    const int mode = (h_cap >= (size_t)N_EDGES * 256) ? 0
                   : (h_cap >= (size_t)N_EDGES * 128) ? 1 : 2;

    const int EB  = N_EDGES / 256;           // 6250 exact
    const int EB2 = N_EDGES / 128;           // 12500 exact (legacy k_edge)
    const int EBM = N_EDGES / 64;            // 25000 exact (mfma k_edge)
    const int NB  = (N_NODES + 255) / 256;   // 391
    const int AB  = (N_NODES + 3) / 4;       // 25001

    hipLaunchKernelGGL(k_init, dim3(NB), dim3(256), 0, stream, stats, deg);

    if (mode == 0) {
        hipLaunchKernelGGL(k_edge<0>, dim3(EB2), dim3(128), 0, stream,
                           x, pos, ei, W1, b1, stats, deg, h, h_cap);
        hipLaunchKernelGGL(k_stats<0>, dim3(1024), dim3(256), 0, stream, h, stats);
        hipLaunchKernelGGL(k_bnfin, dim3(1), dim3(64), 0, stream, stats);
        hipLaunchKernelGGL(k_gate<0>, dim3(EB), dim3(256), 0, stream,
                           h, x, pos, ei, W1, b1, stats, g1, be1, Wg, bg, gate_lin, h_cap);
    } else if (mode == 1) {
        hipLaunchKernelGGL(k_edge_mfma, dim3(EBM), dim3(256), 0, stream,
                           x, pos, ei, W1, b1, stats, deg, h, h_cap);
        hipLaunchKernelGGL(k_bnfin, dim3(1), dim3(64), 0, stream, stats);
        hipLaunchKernelGGL(k_gate<1>, dim3(EB), dim3(256), 0, stream,
                           h, x, pos, ei, W1, b1, stats, g1, be1, Wg, bg, gate_lin, h_cap);
    } else {
        hipLaunchKernelGGL(k_edge<2>, dim3(EB2), dim3(128), 0, stream,
                           x, pos, ei, W1, b1, stats, deg, h, h_cap);
        hipLaunchKernelGGL(k_bnfin, dim3(1), dim3(64), 0, stream, stats);
        hipLaunchKernelGGL(k_gate<2>, dim3(EB), dim3(256), 0, stream,
                           h, x, pos, ei, W1, b1, stats, g1, be1, Wg, bg, gate_lin, h_cap);
    }

    hipLaunchKernelGGL(k_gfin, dim3(1), dim3(64), 0, stream, stats);
    hipLaunchKernelGGL(k_scan, dim3(1), dim3(1024), 0, stream, deg, offs, cursor);
    hipLaunchKernelGGL(k_fill, dim3(EB), dim3(256), 0, stream, ei, cursor, elist);

    if (mode == 0) {
        hipLaunchKernelGGL(k_aggr<0>, dim3(AB), dim3(256), 0, stream,
                           h, h_cap, gate_lin, offs, elist, ei, x, pos, b1, W1,
                           stats, g1, be1, gg, bgb, out);
    } else if (mode == 1) {
        hipLaunchKernelGGL(k_aggr<1>, dim3(AB), dim3(256), 0, stream,
                           h, h_cap, gate_lin, offs, elist, ei, x, pos, b1, W1,
                           stats, g1, be1, gg, bgb, out);
    } else {
        hipLaunchKernelGGL(k_aggr<2>, dim3(AB), dim3(256), 0, stream,
                           h, h_cap, gate_lin, offs, elist, ei, x, pos, b1, W1,
                           stats, g1, be1, gg, bgb, out);
    }
}

// Round 10
// 1100.623 us; speedup vs baseline: 1.9946x; 1.2326x over previous
//
#include <hip/hip_runtime.h>
#include <hip/hip_bf16.h>
#include <math.h>

// Problem constants (fixed by reference)
constexpr int N_NODES = 100000;
constexpr int N_EDGES = 1600000;
constexpr int IN_CH   = 61;
constexpr float BN_EPS = 1e-5f;
constexpr int NPART   = 32;   // atomic spread slots

// stats layout (floats), total 4352:
//  [0..63] mu_h   [64..127] rs_h   [128] gmu [129] grs
//  [192..) part_h: slot s -> [192+s*128+c]=sum_c, [+64+c]=sumsq_c
//  [4288..) part_g: slot s -> [4288+2s]=sum, [+1]=sumsq
constexpr int S_PH = 192;
constexpr int S_PG = 192 + NPART * 128;      // 4288
constexpr int S_TOT = S_PG + NPART * 2;      // 4352

typedef float f32x4 __attribute__((ext_vector_type(4)));
typedef short s16x8 __attribute__((ext_vector_type(8)));

__device__ __forceinline__ float silu(float x) { return x / (1.0f + expf(-x)); }

__device__ __forceinline__ float bf2f(unsigned v) { return __uint_as_float(v << 16); }
__device__ __forceinline__ unsigned f2bf(float f) {
    unsigned u = __float_as_uint(f);
    return (u + 0x7FFFu + ((u >> 16) & 1u)) >> 16;   // RNE
}

// Full-64 matvec helper — used only by MODE 2 / mode 0 legacy paths.
__device__ __forceinline__ bool edge_gemm(
    int e, const float* __restrict__ x, const float* __restrict__ pos,
    const int* __restrict__ ei, const float* __restrict__ W1,
    const float* __restrict__ b1, float* acc, int* jd_out)
{
    int js = ei[e];
    int jd = ei[N_EDGES + e];
    *jd_out = jd;
    bool valid = ((unsigned)js < (unsigned)N_NODES) && ((unsigned)jd < (unsigned)N_NODES);
    if (!valid) {
        #pragma unroll
        for (int c = 0; c < 64; ++c) acc[c] = 0.0f;
        return false;
    }
    #pragma unroll
    for (int c = 0; c < 64; ++c) acc[c] = b1[c];
    const float* xr = x + (size_t)js * IN_CH;
    #pragma unroll 4
    for (int k = 0; k < IN_CH; ++k) {
        float fk = xr[k];
        #pragma unroll
        for (int c = 0; c < 64; ++c) acc[c] += fk * W1[k * 64 + c];
    }
    #pragma unroll
    for (int j = 0; j < 3; ++j) {
        float fk = pos[js * 3 + j] - pos[jd * 3 + j];
        #pragma unroll
        for (int c = 0; c < 64; ++c) acc[c] += fk * W1[(IN_CH + j) * 64 + c];
    }
    return true;
}

// ---- K0: init stats + deg ----
__global__ __launch_bounds__(256) void k_init(float* stats, int* deg) {
    int i = blockIdx.x * 256 + threadIdx.x;
    if (i < S_TOT) stats[i] = 0.0f;
    if (i < N_NODES) deg[i] = 0;
}

// ---- K_prep: W1 -> bf16 hi/lo in MFMA B-fragment order (runs once per launch).
//  slot (ct,kc,lane,j): element W1^T[c][k], c=ct*16+(lane&15), k=kc*32+(lane>>4)*8+j.
//  wf[((ct*2+kc)*64+lane)*8+j]; hi at [0..4095], lo at [4096..8191]. ----
__global__ __launch_bounds__(256) void k_prep(const float* __restrict__ W1,
                                              short* __restrict__ wf)
{
    int i = blockIdx.x * 256 + threadIdx.x;   // 16 blocks x 256 = 4096 slots
    int j    = i & 7;
    int lane = (i >> 3) & 63;
    int kc   = (i >> 9) & 1;
    int ct   = i >> 10;
    int c = ct * 16 + (lane & 15);
    int k = kc * 32 + (lane >> 4) * 8 + j;
    float v = W1[k * 64 + c];
    unsigned hi = f2bf(v);
    unsigned lo = f2bf(v - bf2f(hi));
    wf[i] = (short)hi;
    wf[4096 + i] = (short)lo;
}

// ---- K1 v5 (mode 1): MFMA edge GEMM, 64 edges/block, 4 waves.
//  B-fragments from precomputed global wf (L1-hot, no per-block W1 staging).
//  h written direct from acc (no hs tile); fused stats via shfl+LDS atomics.
//  LDS 18.9KB -> 8 blocks/CU; one barrier total. ----
__global__ __launch_bounds__(256) void k_edge_mfma(
    const float* __restrict__ x, const float* __restrict__ pos,
    const int* __restrict__ ei, const short* __restrict__ wf,
    const float* __restrict__ b1, float* __restrict__ stats,
    int* __restrict__ deg, void* __restrict__ h, size_t h_cap)
{
    __shared__ __align__(16) short fsh[64][72];   // f hi (bf16), pad 72
    __shared__ __align__(16) short fsl[64][72];   // f lo
    __shared__ float lsum[128];                   // fused stats partials

    const int tid  = threadIdx.x;
    const int w    = tid >> 6, lane = tid & 63;
    const int e0   = blockIdx.x * 64;             // grid exact: E/64

    if (tid < 128) lsum[tid] = 0.0f;

    // --- indices + deg histogram (16 edges per wave) ---
    int js_l = 0, jd_l = 0;
    if (lane < 16) {
        int e = e0 + w * 16 + lane;
        js_l = ei[e];
        jd_l = ei[N_EDGES + e];
        if ((unsigned)js_l >= (unsigned)N_NODES) js_l = 0;
        if ((unsigned)jd_l >= (unsigned)N_NODES) jd_l = 0;
        atomicAdd(&deg[jd_l], 1);
    }

    // --- stage f rows (wave-private: wave w writes AND reads rows w*16..+15) ---
    #pragma unroll 4
    for (int j = 0; j < 16; ++j) {
        int js = __shfl(js_l, j);
        int jd = __shfl(jd_l, j);
        int r  = w * 16 + j;
        float v;
        if (lane < IN_CH) v = x[(size_t)js * IN_CH + lane];
        else              v = pos[js * 3 + (lane - IN_CH)] - pos[jd * 3 + (lane - IN_CH)];
        unsigned hi = f2bf(v);
        unsigned lo = f2bf(v - bf2f(hi));
        fsh[r][lane] = (short)hi;
        fsl[r][lane] = (short)lo;
    }
    __syncthreads();      // covers lsum zeroing; staging is wave-private anyway

    // --- MFMA: wave w computes rows w*16..+15 x all 64 channels ---
    const int r = lane & 15, g = lane >> 4;
    const int arow = w * 16 + r;
    s16x8 ah0 = *(const s16x8*)&fsh[arow][g * 8];
    s16x8 ah1 = *(const s16x8*)&fsh[arow][32 + g * 8];
    s16x8 al0 = *(const s16x8*)&fsl[arow][g * 8];
    s16x8 al1 = *(const s16x8*)&fsl[arow][32 + g * 8];

    const bool do_h = ((size_t)(e0 + 64) * 128 <= h_cap);
    unsigned short* hp = (unsigned short*)h;

    #pragma unroll
    for (int ct = 0; ct < 4; ++ct) {
        int c = ct * 16 + r;
        // B-fragments: coalesced 16B global loads, broadcast-hot in L1/L2
        s16x8 bh0 = *(const s16x8*)&wf[((ct * 2 + 0) * 64 + lane) * 8];
        s16x8 bh1 = *(const s16x8*)&wf[((ct * 2 + 1) * 64 + lane) * 8];
        s16x8 bl0 = *(const s16x8*)&wf[4096 + ((ct * 2 + 0) * 64 + lane) * 8];
        s16x8 bl1 = *(const s16x8*)&wf[4096 + ((ct * 2 + 1) * 64 + lane) * 8];
        f32x4 acc = {0.0f, 0.0f, 0.0f, 0.0f};
        acc = __builtin_amdgcn_mfma_f32_16x16x32_bf16(al0, bh0, acc, 0, 0, 0);
        acc = __builtin_amdgcn_mfma_f32_16x16x32_bf16(al1, bh1, acc, 0, 0, 0);
        acc = __builtin_amdgcn_mfma_f32_16x16x32_bf16(ah0, bl0, acc, 0, 0, 0);
        acc = __builtin_amdgcn_mfma_f32_16x16x32_bf16(ah1, bl1, acc, 0, 0, 0);
        acc = __builtin_amdgcn_mfma_f32_16x16x32_bf16(ah0, bh0, acc, 0, 0, 0);
        acc = __builtin_amdgcn_mfma_f32_16x16x32_bf16(ah1, bh1, acc, 0, 0, 0);
        float bias = b1[c];
        float s = 0.0f, q = 0.0f;
        #pragma unroll
        for (int i = 0; i < 4; ++i) {
            unsigned hb = f2bf(acc[i] + bias);
            float v = bf2f(hb);               // stats from bf16-rounded h
            s += v; q += v * v;
            if (do_h) {
                int row = w * 16 + g * 4 + i;
                hp[(size_t)(e0 + row) * 64 + c] = (unsigned short)hb;
            }
        }
        // reduce over g (4 row-groups hold same channel c)
        s += __shfl_xor(s, 16); s += __shfl_xor(s, 32);
        q += __shfl_xor(q, 16); q += __shfl_xor(q, 32);
        if (g == 0) {
            atomicAdd(&lsum[c], s);
            atomicAdd(&lsum[64 + c], q);
        }
    }
    __syncthreads();
    if (tid < 128)
        atomicAdd(&stats[S_PH + (blockIdx.x & (NPART - 1)) * 128 + tid], lsum[tid]);
}

// ---- K1 legacy (modes 0/2): LDS-staged scalar path ----
template<int MODE>
__global__ __launch_bounds__(128) void k_edge(
    const float* __restrict__ x, const float* __restrict__ pos,
    const int* __restrict__ ei, const float* __restrict__ W1,
    const float* __restrict__ b1, float* __restrict__ stats,
    int* __restrict__ deg, void* __restrict__ h, size_t h_cap)
{
    constexpr int EPB = 128;
    __shared__ float fs[EPB][65];
    __shared__ float ls[128];

    const int tid  = threadIdx.x;
    const int wave = tid >> 6, lane = tid & 63;
    const int eb   = blockIdx.x * EPB;
    const int r0   = wave * 64;

    const int eg = eb + r0 + lane;
    int js_l = ei[eg];
    int jd_l = ei[N_EDGES + eg];
    bool valid = ((unsigned)js_l < (unsigned)N_NODES) &&
                 ((unsigned)jd_l < (unsigned)N_NODES);
    if (valid) atomicAdd(&deg[jd_l], 1);

    if constexpr (MODE == 2) {
        if (tid < 128) ls[tid] = 0.0f;
    }

    for (int j = 0; j < 64; ++j) {
        int js = __shfl(js_l, j);
        int jd = __shfl(jd_l, j);
        int ok = __shfl((int)valid, j);
        int r = r0 + j;
        if (lane < IN_CH) {
            fs[r][lane] = ok ? x[(size_t)js * IN_CH + lane] : 0.0f;
        } else {
            int d = lane - IN_CH;
            fs[r][lane] = ok ? (pos[js * 3 + d] - pos[jd * 3 + d]) : 0.0f;
        }
    }
    __syncthreads();

    #pragma unroll 1
    for (int half = 0; half < 2; ++half) {
        const int base = half * 32;
        float acc[32];
        #pragma unroll
        for (int c = 0; c < 32; ++c) acc[c] = valid ? b1[base + c] : 0.0f;
        if (valid) {
            #pragma unroll 4
            for (int k = 0; k < 64; ++k) {
                float fk = fs[tid][k];
                #pragma unroll
                for (int c = 0; c < 32; ++c)
                    acc[c] += fk * W1[k * 64 + base + c];
            }
        }
        if constexpr (MODE == 0) {
            if ((size_t)(eb + tid + 1) * 256 <= h_cap) {
                float4* hq = (float4*)((char*)h + (size_t)(eb + tid) * 256
                                       + (size_t)base * 4);
                #pragma unroll
                for (int i = 0; i < 8; ++i)
                    hq[i] = make_float4(acc[4*i], acc[4*i+1], acc[4*i+2], acc[4*i+3]);
            }
        } else {
            #pragma unroll
            for (int c = 0; c < 32; ++c) {
                atomicAdd(&ls[base + c], acc[c]);
                atomicAdd(&ls[64 + base + c], acc[c] * acc[c]);
            }
        }
    }

    if constexpr (MODE == 2) {
        __syncthreads();
        if (tid < 128)
            atomicAdd(&stats[S_PH + (blockIdx.x & (NPART-1)) * 128 + tid], ls[tid]);
    }
}

// ---- K2: per-channel sum/sumsq streaming over h (mode 0 only now) ----
template<int MODE>
__global__ __launch_bounds__(256) void k_stats(const void* __restrict__ h,
                                               float* __restrict__ stats)
{
    constexpr int VEC = (MODE == 0) ? 4 : 8;
    const size_t nvec = (size_t)N_EDGES * 64 / VEC;
    size_t stride = (size_t)gridDim.x * 256;
    size_t g0 = (size_t)blockIdx.x * 256 + threadIdx.x;
    int c0 = (int)((g0 * VEC) & 63);
    float sum[VEC], sq[VEC];
    #pragma unroll
    for (int j = 0; j < VEC; ++j) { sum[j] = 0.0f; sq[j] = 0.0f; }

    for (size_t v = g0; v < nvec; v += stride) {
        float vals[VEC];
        if constexpr (MODE == 0) {
            float4 t = ((const float4*)h)[v];
            vals[0] = t.x; vals[1] = t.y; vals[2] = t.z; vals[3] = t.w;
        } else {
            uint4 t = ((const uint4*)h)[v];
            vals[0] = bf2f(t.x & 0xFFFF); vals[1] = bf2f(t.x >> 16);
            vals[2] = bf2f(t.y & 0xFFFF); vals[3] = bf2f(t.y >> 16);
            vals[4] = bf2f(t.z & 0xFFFF); vals[5] = bf2f(t.z >> 16);
            vals[6] = bf2f(t.w & 0xFFFF); vals[7] = bf2f(t.w >> 16);
        }
        #pragma unroll
        for (int j = 0; j < VEC; ++j) { sum[j] += vals[j]; sq[j] += vals[j] * vals[j]; }
    }
    __shared__ float ls[128];
    if (threadIdx.x < 128) ls[threadIdx.x] = 0.0f;
    __syncthreads();
    #pragma unroll
    for (int j = 0; j < VEC; ++j) {
        atomicAdd(&ls[c0 + j], sum[j]);
        atomicAdd(&ls[64 + c0 + j], sq[j]);
    }
    __syncthreads();
    if (threadIdx.x < 128)
        atomicAdd(&stats[S_PH + (blockIdx.x & (NPART-1)) * 128 + threadIdx.x],
                  ls[threadIdx.x]);
}

// ---- K3: reduce part_h -> mu/rs ----
__global__ void k_bnfin(float* stats) {
    int c = threadIdx.x;
    if (c < 64) {
        float s = 0.0f, q = 0.0f;
        #pragma unroll
        for (int p = 0; p < NPART; ++p) {
            s += stats[S_PH + p * 128 + c];
            q += stats[S_PH + p * 128 + 64 + c];
        }
        float m = s / (float)N_EDGES;
        float v = q / (float)N_EDGES - m * m;
        stats[c] = m;
        stats[64 + c] = rsqrtf(v + BN_EPS);
    }
}

// ---- K4: gate_lin per edge + gate batch stats ----
template<int MODE>
__global__ __launch_bounds__(256) void k_gate(
    const void* __restrict__ h, const float* __restrict__ x,
    const float* __restrict__ pos, const int* __restrict__ ei,
    const float* __restrict__ W1, const float* __restrict__ b1,
    float* __restrict__ stats, const float* __restrict__ g1,
    const float* __restrict__ be1, const float* __restrict__ Wg,
    const float* __restrict__ bg, float* __restrict__ gate_lin, size_t h_cap)
{
    int e = blockIdx.x * 256 + threadIdx.x;
    float gl = bg[0];

    if constexpr (MODE == 2) {
        float hv[64];
        int jd;
        edge_gemm(e, x, pos, ei, W1, b1, hv, &jd);
        #pragma unroll
        for (int c = 0; c < 64; ++c) {
            float t = (hv[c] - stats[c]) * stats[64 + c] * g1[c] + be1[c];
            gl += silu(t) * Wg[c];
        }
    } else if constexpr (MODE == 0) {
        if ((size_t)(e + 1) * 256 <= h_cap) {
            const float4* hq = (const float4*)((const char*)h + (size_t)e * 256);
            #pragma unroll
            for (int i = 0; i < 16; ++i) {
                float4 t = hq[i];
                float vv[4] = {t.x, t.y, t.z, t.w};
                #pragma unroll
                for (int j = 0; j < 4; ++j) {
                    int c = 4 * i + j;
                    float tt = (vv[j] - stats[c]) * stats[64 + c] * g1[c] + be1[c];
                    gl += silu(tt) * Wg[c];
                }
            }
        }
    } else {
        if ((size_t)(e + 1) * 128 <= h_cap) {
            const uint4* hq = (const uint4*)((const char*)h + (size_t)e * 128);
            #pragma unroll
            for (int j = 0; j < 8; ++j) {
                uint4 t = hq[j];
                float vv[8];
                vv[0] = bf2f(t.x & 0xFFFF); vv[1] = bf2f(t.x >> 16);
                vv[2] = bf2f(t.y & 0xFFFF); vv[3] = bf2f(t.y >> 16);
                vv[4] = bf2f(t.z & 0xFFFF); vv[5] = bf2f(t.z >> 16);
                vv[6] = bf2f(t.w & 0xFFFF); vv[7] = bf2f(t.w >> 16);
                #pragma unroll
                for (int q = 0; q < 8; ++q) {
                    int c = 8 * j + q;
                    float tt = (vv[q] - stats[c]) * stats[64 + c] * g1[c] + be1[c];
                    gl += silu(tt) * Wg[c];
                }
            }
        }
    }
    gate_lin[e] = gl;

    float s1 = gl, s2 = gl * gl;
    #pragma unroll
    for (int off = 32; off >= 1; off >>= 1) {
        s1 += __shfl_xor(s1, off);
        s2 += __shfl_xor(s2, off);
    }
    __shared__ float red[8];
    int w = threadIdx.x >> 6, lane = threadIdx.x & 63;
    if (lane == 0) { red[w] = s1; red[4 + w] = s2; }
    __syncthreads();
    if (threadIdx.x == 0) {
        int slot = S_PG + (blockIdx.x & (NPART-1)) * 2;
        atomicAdd(&stats[slot], red[0] + red[1] + red[2] + red[3]);
        atomicAdd(&stats[slot + 1], red[4] + red[5] + red[6] + red[7]);
    }
}

// ---- K5: reduce part_g -> gmu/grs ----
__global__ void k_gfin(float* stats) {
    if (threadIdx.x == 0) {
        float s = 0.0f, q = 0.0f;
        for (int p = 0; p < NPART; ++p) {
            s += stats[S_PG + 2 * p];
            q += stats[S_PG + 2 * p + 1];
        }
        float m = s / (float)N_EDGES;
        float v = q / (float)N_EDGES - m * m;
        stats[128] = m;
        stats[129] = rsqrtf(v + BN_EPS);
    }
}

// ---- K6: single-block scan deg -> offs, cursor ----
__global__ __launch_bounds__(1024) void k_scan(const int* __restrict__ deg,
                                               int* __restrict__ offs,
                                               int* __restrict__ cursor)
{
    __shared__ int ps[1024];
    int t = threadIdx.x;
    const int CH = (N_NODES + 1023) / 1024;
    int lo = t * CH, hi = lo + CH;
    if (hi > N_NODES) hi = N_NODES;
    if (lo > N_NODES) lo = N_NODES;
    int s = 0;
    for (int i = lo; i < hi; ++i) s += deg[i];
    ps[t] = s;
    __syncthreads();
    for (int off = 1; off < 1024; off <<= 1) {
        int v = (t >= off) ? ps[t - off] : 0;
        __syncthreads();
        ps[t] += v;
        __syncthreads();
    }
    int run = (t == 0) ? 0 : ps[t - 1];
    for (int i = lo; i < hi; ++i) {
        offs[i] = run;
        cursor[i] = run;
        run += deg[i];
    }
    if (t == 1023) offs[N_NODES] = ps[1023];
}

// ---- K7: CSR fill ----
__global__ __launch_bounds__(256) void k_fill(const int* __restrict__ ei,
                                              int* __restrict__ cursor,
                                              int* __restrict__ elist)
{
    int e = blockIdx.x * 256 + threadIdx.x;
    int js = ei[e];
    int d = ei[N_EDGES + e];
    if ((unsigned)js >= (unsigned)N_NODES || (unsigned)d >= (unsigned)N_NODES) return;
    int p = atomicAdd(&cursor[d], 1);
    if ((unsigned)p < (unsigned)N_EDGES) elist[p] = e;
}

// ---- K8: wave per node, lane = channel; 1-deep software pipeline (modes 0/1) ----
template<int MODE>
__device__ __forceinline__ void aggr_body(
    const void* __restrict__ h, size_t h_cap, const float* __restrict__ gate_lin,
    const int* __restrict__ offs, const int* __restrict__ elist,
    const int* __restrict__ ei, const float* __restrict__ x,
    const float* __restrict__ pos, const float* __restrict__ b1,
    const float* W1s, const float* __restrict__ stats,
    const float* __restrict__ g1, const float* __restrict__ be1,
    const float* __restrict__ gg, const float* __restrict__ bgb,
    float* __restrict__ out)
{
    int wid = (blockIdx.x * 256 + threadIdx.x) >> 6;
    int lane = threadIdx.x & 63;
    if (wid >= N_NODES) return;

    float mu = stats[lane], rs = stats[64 + lane];
    float gmu = stats[128], grs = stats[129];
    float ga = g1[lane], bb = be1[lane];
    float gga = gg[0], gbb = bgb[0];

    int lo = offs[wid], hi = offs[wid + 1];
    float accv = 0.0f, wsum = 0.0f;

    if constexpr (MODE == 2) {
        float b1v = b1[lane];
        float pim = (lane >= IN_CH) ? pos[wid * 3 + (lane - IN_CH)] : 0.0f;
        for (int i = lo; i < hi; ++i) {
            int e = elist[i];
            float gl = gate_lin[e];
            float tg = (gl - gmu) * grs * gga + gbb;
            float w = expf(silu(tg));
            int js = ei[e];
            if ((unsigned)js >= (unsigned)N_NODES) continue;
            float fl = (lane < IN_CH) ? x[(size_t)js * IN_CH + lane]
                                      : pos[js * 3 + (lane - IN_CH)] - pim;
            float a = b1v;
            #pragma unroll
            for (int k = 0; k < 64; ++k) a += __shfl(fl, k) * W1s[k * 64 + lane];
            float tn = (a - mu) * rs * ga + bb;
            accv += w * silu(tn);
            wsum += w;
        }
    } else {
        auto load_h = [&](int e) -> float {
            if constexpr (MODE == 0) {
                if ((size_t)(e + 1) * 256 > h_cap) return 0.0f;
                return ((const float*)h)[(size_t)e * 64 + lane];
            } else {
                if ((size_t)(e + 1) * 128 > h_cap) return 0.0f;
                return bf2f(((const unsigned short*)h)[(size_t)e * 64 + lane]);
            }
        };
        if (lo < hi) {
            int e = elist[lo];
            float gl = gate_lin[e];
            float hval = load_h(e);
            for (int i = lo; i < hi; ++i) {
                int en = 0; float gln = 0.0f, hn = 0.0f;
                if (i + 1 < hi) {
                    en = elist[i + 1];
                    gln = gate_lin[en];
                    hn = load_h(en);
                }
                float tg = (gl - gmu) * grs * gga + gbb;
                float w = expf(silu(tg));
                float tn = (hval - mu) * rs * ga + bb;
                accv += w * silu(tn);
                wsum += w;
                e = en; gl = gln; hval = hn;
            }
        }
    }
    out[(size_t)wid * 64 + lane] = accv / (wsum + 1e-16f);
}

template<int MODE>
__global__ __launch_bounds__(256) void k_aggr(
    const void* __restrict__ h, size_t h_cap, const float* __restrict__ gate_lin,
    const int* __restrict__ offs, const int* __restrict__ elist,
    const int* __restrict__ ei, const float* __restrict__ x,
    const float* __restrict__ pos, const float* __restrict__ b1,
    const float* __restrict__ W1, const float* __restrict__ stats,
    const float* __restrict__ g1, const float* __restrict__ be1,
    const float* __restrict__ gg, const float* __restrict__ bgb,
    float* __restrict__ out)
{
    if constexpr (MODE == 2) {
        __shared__ float W1s[4096];
        for (int i = threadIdx.x; i < 4096; i += 256) W1s[i] = W1[i];
        __syncthreads();
        aggr_body<2>(h, h_cap, gate_lin, offs, elist, ei, x, pos, b1, W1s,
                     stats, g1, be1, gg, bgb, out);
    } else {
        aggr_body<MODE>(h, h_cap, gate_lin, offs, elist, ei, x, pos, b1, nullptr,
                        stats, g1, be1, gg, bgb, out);
    }
}

extern "C" void kernel_launch(void* const* d_in, const int* in_sizes, int n_in,
                              void* d_out, int out_size, void* d_ws, size_t ws_size,
                              hipStream_t stream)
{
    const float* x   = (const float*)d_in[0];
    const float* pos = (const float*)d_in[1];
    const int*   ei  = (const int*)d_in[2];
    const float* W1  = (const float*)d_in[3];
    const float* b1  = (const float*)d_in[4];
    const float* g1  = (const float*)d_in[5];
    const float* be1 = (const float*)d_in[6];
    const float* Wg  = (const float*)d_in[7];
    const float* bg  = (const float*)d_in[8];
    const float* gg  = (const float*)d_in[9];
    const float* bgb = (const float*)d_in[10];
    float* out = (float*)d_out;

    char* base = (char*)d_ws;
    size_t off = 0;
    auto alloc = [&](size_t bytes) {
        size_t o = off;
        off = (off + bytes + 255) & ~(size_t)255;
        return o;
    };
    float* stats    = (float*)(base + alloc(S_TOT * 4));
    int*   deg      = (int*)(base + alloc((size_t)N_NODES * 4));
    int*   offs     = (int*)(base + alloc((size_t)(N_NODES + 1) * 4));
    int*   cursor   = (int*)(base + alloc((size_t)N_NODES * 4));
    int*   elist    = (int*)(base + alloc((size_t)N_EDGES * 4));
    float* gate_lin = (float*)(base + alloc((size_t)N_EDGES * 4));
    short* wfrag    = (short*)(base + alloc(8192 * 2));     // W1 bf16 hi/lo fragments
    if (ws_size < off) return;
    void*  h     = (void*)(base + off);
    size_t h_cap = ws_size - off;

    const int mode = (h_cap >= (size_t)N_EDGES * 256) ? 0
                   : (h_cap >= (size_t)N_EDGES * 128) ? 1 : 2;

    const int EB  = N_EDGES / 256;           // 6250 exact
    const int EB2 = N_EDGES / 128;           // 12500 exact (legacy k_edge)
    const int EBM = N_EDGES / 64;            // 25000 exact (mfma k_edge)
    const int NB  = (N_NODES + 255) / 256;   // 391
    const int AB  = (N_NODES + 3) / 4;       // 25001

    hipLaunchKernelGGL(k_init, dim3(NB), dim3(256), 0, stream, stats, deg);

    if (mode == 0) {
        hipLaunchKernelGGL(k_edge<0>, dim3(EB2), dim3(128), 0, stream,
                           x, pos, ei, W1, b1, stats, deg, h, h_cap);
        hipLaunchKernelGGL(k_stats<0>, dim3(1024), dim3(256), 0, stream, h, stats);
        hipLaunchKernelGGL(k_bnfin, dim3(1), dim3(64), 0, stream, stats);
        hipLaunchKernelGGL(k_gate<0>, dim3(EB), dim3(256), 0, stream,
                           h, x, pos, ei, W1, b1, stats, g1, be1, Wg, bg, gate_lin, h_cap);
    } else if (mode == 1) {
        hipLaunchKernelGGL(k_prep, dim3(16), dim3(256), 0, stream, W1, wfrag);
        hipLaunchKernelGGL(k_edge_mfma, dim3(EBM), dim3(256), 0, stream,
                           x, pos, ei, wfrag, b1, stats, deg, h, h_cap);
        hipLaunchKernelGGL(k_bnfin, dim3(1), dim3(64), 0, stream, stats);
        hipLaunchKernelGGL(k_gate<1>, dim3(EB), dim3(256), 0, stream,
                           h, x, pos, ei, W1, b1, stats, g1, be1, Wg, bg, gate_lin, h_cap);
    } else {
        hipLaunchKernelGGL(k_edge<2>, dim3(EB2), dim3(128), 0, stream,
                           x, pos, ei, W1, b1, stats, deg, h, h_cap);
        hipLaunchKernelGGL(k_bnfin, dim3(1), dim3(64), 0, stream, stats);
        hipLaunchKernelGGL(k_gate<2>, dim3(EB), dim3(256), 0, stream,
                           h, x, pos, ei, W1, b1, stats, g1, be1, Wg, bg, gate_lin, h_cap);
    }

    hipLaunchKernelGGL(k_gfin, dim3(1), dim3(64), 0, stream, stats);
    hipLaunchKernelGGL(k_scan, dim3(1), dim3(1024), 0, stream, deg, offs, cursor);
    hipLaunchKernelGGL(k_fill, dim3(EB), dim3(256), 0, stream, ei, cursor, elist);

    if (mode == 0) {
        hipLaunchKernelGGL(k_aggr<0>, dim3(AB), dim3(256), 0, stream,
                           h, h_cap, gate_lin, offs, elist, ei, x, pos, b1, W1,
                           stats, g1, be1, gg, bgb, out);
    } else if (mode == 1) {
        hipLaunchKernelGGL(k_aggr<1>, dim3(AB), dim3(256), 0, stream,
                           h, h_cap, gate_lin, offs, elist, ei, x, pos, b1, W1,
                           stats, g1, be1, gg, bgb, out);
    } else {
        hipLaunchKernelGGL(k_aggr<2>, dim3(AB), dim3(256), 0, stream,
                           h, h_cap, gate_lin, offs, elist, ei, x, pos, b1, W1,
                           stats, g1, be1, gg, bgb, out);
    }
}

// Round 11
// 985.152 us; speedup vs baseline: 2.2284x; 1.1172x over previous
//
#include <hip/hip_runtime.h>
#include <hip/hip_bf16.h>
#include <hip/hip_fp16.h>
#include <math.h>

// Problem constants (fixed by reference)
constexpr int N_NODES = 100000;
constexpr int N_EDGES = 1600000;
constexpr int IN_CH   = 61;
constexpr float BN_EPS = 1e-5f;
constexpr int NPART   = 32;   // atomic spread slots

// stats layout (floats), total 4352:
//  [0..63] mu_h   [64..127] rs_h   [128] gmu [129] grs
//  [192..) part_h: slot s -> [192+s*128+c]=sum_c, [+64+c]=sumsq_c
//  [4288..) part_g: slot s -> [4288+2s]=sum, [+1]=sumsq
constexpr int S_PH = 192;
constexpr int S_PG = 192 + NPART * 128;      // 4288
constexpr int S_TOT = S_PG + NPART * 2;      // 4352

typedef float f32x4 __attribute__((ext_vector_type(4)));
typedef short s16x8 __attribute__((ext_vector_type(8)));

// Fast transcendentals: native v_exp_f32 + v_rcp_f32 (~1 ulp; tolerance budget is
// dominated by bf16 h quantization at 0.0156, so this is free accuracy-wise).
__device__ __forceinline__ float fast_exp(float x) { return __expf(x); }
__device__ __forceinline__ float silu(float x) {
    return x * __builtin_amdgcn_rcpf(1.0f + __expf(-x));
}

__device__ __forceinline__ float bf2f(unsigned v) { return __uint_as_float(v << 16); }
__device__ __forceinline__ unsigned f2bf(float f) {
    unsigned u = __float_as_uint(f);
    return (u + 0x7FFFu + ((u >> 16) & 1u)) >> 16;   // RNE
}

// Full-64 matvec helper — used only by MODE 2 / mode 0 legacy paths.
__device__ __forceinline__ bool edge_gemm(
    int e, const float* __restrict__ x, const float* __restrict__ pos,
    const int* __restrict__ ei, const float* __restrict__ W1,
    const float* __restrict__ b1, float* acc, int* jd_out)
{
    int js = ei[e];
    int jd = ei[N_EDGES + e];
    *jd_out = jd;
    bool valid = ((unsigned)js < (unsigned)N_NODES) && ((unsigned)jd < (unsigned)N_NODES);
    if (!valid) {
        #pragma unroll
        for (int c = 0; c < 64; ++c) acc[c] = 0.0f;
        return false;
    }
    #pragma unroll
    for (int c = 0; c < 64; ++c) acc[c] = b1[c];
    const float* xr = x + (size_t)js * IN_CH;
    #pragma unroll 4
    for (int k = 0; k < IN_CH; ++k) {
        float fk = xr[k];
        #pragma unroll
        for (int c = 0; c < 64; ++c) acc[c] += fk * W1[k * 64 + c];
    }
    #pragma unroll
    for (int j = 0; j < 3; ++j) {
        float fk = pos[js * 3 + j] - pos[jd * 3 + j];
        #pragma unroll
        for (int c = 0; c < 64; ++c) acc[c] += fk * W1[(IN_CH + j) * 64 + c];
    }
    return true;
}

// ---- K0: init stats + deg ----
__global__ __launch_bounds__(256) void k_init(float* stats, int* deg) {
    int i = blockIdx.x * 256 + threadIdx.x;
    if (i < S_TOT) stats[i] = 0.0f;
    if (i < N_NODES) deg[i] = 0;
}

// ---- K_prep: W1 -> bf16 hi/lo in MFMA B-fragment order (runs once per launch). ----
__global__ __launch_bounds__(256) void k_prep(const float* __restrict__ W1,
                                              short* __restrict__ wf)
{
    int i = blockIdx.x * 256 + threadIdx.x;   // 16 blocks x 256 = 4096 slots
    int j    = i & 7;
    int lane = (i >> 3) & 63;
    int kc   = (i >> 9) & 1;
    int ct   = i >> 10;
    int c = ct * 16 + (lane & 15);
    int k = kc * 32 + (lane >> 4) * 8 + j;
    float v = W1[k * 64 + c];
    unsigned hi = f2bf(v);
    unsigned lo = f2bf(v - bf2f(hi));
    wf[i] = (short)hi;
    wf[4096 + i] = (short)lo;
}

// ---- K1 v5 (mode 1): MFMA edge GEMM, 64 edges/block, 4 waves. (unchanged) ----
__global__ __launch_bounds__(256) void k_edge_mfma(
    const float* __restrict__ x, const float* __restrict__ pos,
    const int* __restrict__ ei, const short* __restrict__ wf,
    const float* __restrict__ b1, float* __restrict__ stats,
    int* __restrict__ deg, void* __restrict__ h, size_t h_cap)
{
    __shared__ __align__(16) short fsh[64][72];   // f hi (bf16), pad 72
    __shared__ __align__(16) short fsl[64][72];   // f lo
    __shared__ float lsum[128];                   // fused stats partials

    const int tid  = threadIdx.x;
    const int w    = tid >> 6, lane = tid & 63;
    const int e0   = blockIdx.x * 64;             // grid exact: E/64

    if (tid < 128) lsum[tid] = 0.0f;

    int js_l = 0, jd_l = 0;
    if (lane < 16) {
        int e = e0 + w * 16 + lane;
        js_l = ei[e];
        jd_l = ei[N_EDGES + e];
        if ((unsigned)js_l >= (unsigned)N_NODES) js_l = 0;
        if ((unsigned)jd_l >= (unsigned)N_NODES) jd_l = 0;
        atomicAdd(&deg[jd_l], 1);
    }

    #pragma unroll 4
    for (int j = 0; j < 16; ++j) {
        int js = __shfl(js_l, j);
        int jd = __shfl(jd_l, j);
        int r  = w * 16 + j;
        float v;
        if (lane < IN_CH) v = x[(size_t)js * IN_CH + lane];
        else              v = pos[js * 3 + (lane - IN_CH)] - pos[jd * 3 + (lane - IN_CH)];
        unsigned hi = f2bf(v);
        unsigned lo = f2bf(v - bf2f(hi));
        fsh[r][lane] = (short)hi;
        fsl[r][lane] = (short)lo;
    }
    __syncthreads();

    const int r = lane & 15, g = lane >> 4;
    const int arow = w * 16 + r;
    s16x8 ah0 = *(const s16x8*)&fsh[arow][g * 8];
    s16x8 ah1 = *(const s16x8*)&fsh[arow][32 + g * 8];
    s16x8 al0 = *(const s16x8*)&fsl[arow][g * 8];
    s16x8 al1 = *(const s16x8*)&fsl[arow][32 + g * 8];

    const bool do_h = ((size_t)(e0 + 64) * 128 <= h_cap);
    unsigned short* hp = (unsigned short*)h;

    #pragma unroll
    for (int ct = 0; ct < 4; ++ct) {
        int c = ct * 16 + r;
        s16x8 bh0 = *(const s16x8*)&wf[((ct * 2 + 0) * 64 + lane) * 8];
        s16x8 bh1 = *(const s16x8*)&wf[((ct * 2 + 1) * 64 + lane) * 8];
        s16x8 bl0 = *(const s16x8*)&wf[4096 + ((ct * 2 + 0) * 64 + lane) * 8];
        s16x8 bl1 = *(const s16x8*)&wf[4096 + ((ct * 2 + 1) * 64 + lane) * 8];
        f32x4 acc = {0.0f, 0.0f, 0.0f, 0.0f};
        acc = __builtin_amdgcn_mfma_f32_16x16x32_bf16(al0, bh0, acc, 0, 0, 0);
        acc = __builtin_amdgcn_mfma_f32_16x16x32_bf16(al1, bh1, acc, 0, 0, 0);
        acc = __builtin_amdgcn_mfma_f32_16x16x32_bf16(ah0, bl0, acc, 0, 0, 0);
        acc = __builtin_amdgcn_mfma_f32_16x16x32_bf16(ah1, bl1, acc, 0, 0, 0);
        acc = __builtin_amdgcn_mfma_f32_16x16x32_bf16(ah0, bh0, acc, 0, 0, 0);
        acc = __builtin_amdgcn_mfma_f32_16x16x32_bf16(ah1, bh1, acc, 0, 0, 0);
        float bias = b1[c];
        float s = 0.0f, q = 0.0f;
        #pragma unroll
        for (int i = 0; i < 4; ++i) {
            unsigned hb = f2bf(acc[i] + bias);
            float v = bf2f(hb);               // stats from bf16-rounded h
            s += v; q += v * v;
            if (do_h) {
                int row = w * 16 + g * 4 + i;
                hp[(size_t)(e0 + row) * 64 + c] = (unsigned short)hb;
            }
        }
        s += __shfl_xor(s, 16); s += __shfl_xor(s, 32);
        q += __shfl_xor(q, 16); q += __shfl_xor(q, 32);
        if (g == 0) {
            atomicAdd(&lsum[c], s);
            atomicAdd(&lsum[64 + c], q);
        }
    }
    __syncthreads();
    if (tid < 128)
        atomicAdd(&stats[S_PH + (blockIdx.x & (NPART - 1)) * 128 + tid], lsum[tid]);
}

// ---- K1 legacy (modes 0/2): LDS-staged scalar path ----
template<int MODE>
__global__ __launch_bounds__(128) void k_edge(
    const float* __restrict__ x, const float* __restrict__ pos,
    const int* __restrict__ ei, const float* __restrict__ W1,
    const float* __restrict__ b1, float* __restrict__ stats,
    int* __restrict__ deg, void* __restrict__ h, size_t h_cap)
{
    constexpr int EPB = 128;
    __shared__ float fs[EPB][65];
    __shared__ float ls[128];

    const int tid  = threadIdx.x;
    const int wave = tid >> 6, lane = tid & 63;
    const int eb   = blockIdx.x * EPB;
    const int r0   = wave * 64;

    const int eg = eb + r0 + lane;
    int js_l = ei[eg];
    int jd_l = ei[N_EDGES + eg];
    bool valid = ((unsigned)js_l < (unsigned)N_NODES) &&
                 ((unsigned)jd_l < (unsigned)N_NODES);
    if (valid) atomicAdd(&deg[jd_l], 1);

    if constexpr (MODE == 2) {
        if (tid < 128) ls[tid] = 0.0f;
    }

    for (int j = 0; j < 64; ++j) {
        int js = __shfl(js_l, j);
        int jd = __shfl(jd_l, j);
        int ok = __shfl((int)valid, j);
        int r = r0 + j;
        if (lane < IN_CH) {
            fs[r][lane] = ok ? x[(size_t)js * IN_CH + lane] : 0.0f;
        } else {
            int d = lane - IN_CH;
            fs[r][lane] = ok ? (pos[js * 3 + d] - pos[jd * 3 + d]) : 0.0f;
        }
    }
    __syncthreads();

    #pragma unroll 1
    for (int half = 0; half < 2; ++half) {
        const int base = half * 32;
        float acc[32];
        #pragma unroll
        for (int c = 0; c < 32; ++c) acc[c] = valid ? b1[base + c] : 0.0f;
        if (valid) {
            #pragma unroll 4
            for (int k = 0; k < 64; ++k) {
                float fk = fs[tid][k];
                #pragma unroll
                for (int c = 0; c < 32; ++c)
                    acc[c] += fk * W1[k * 64 + base + c];
            }
        }
        if constexpr (MODE == 0) {
            if ((size_t)(eb + tid + 1) * 256 <= h_cap) {
                float4* hq = (float4*)((char*)h + (size_t)(eb + tid) * 256
                                       + (size_t)base * 4);
                #pragma unroll
                for (int i = 0; i < 8; ++i)
                    hq[i] = make_float4(acc[4*i], acc[4*i+1], acc[4*i+2], acc[4*i+3]);
            }
        } else {
            #pragma unroll
            for (int c = 0; c < 32; ++c) {
                atomicAdd(&ls[base + c], acc[c]);
                atomicAdd(&ls[64 + base + c], acc[c] * acc[c]);
            }
        }
    }

    if constexpr (MODE == 2) {
        __syncthreads();
        if (tid < 128)
            atomicAdd(&stats[S_PH + (blockIdx.x & (NPART-1)) * 128 + tid], ls[tid]);
    }
}

// ---- K2: per-channel sum/sumsq streaming over h (mode 0 only) ----
template<int MODE>
__global__ __launch_bounds__(256) void k_stats(const void* __restrict__ h,
                                               float* __restrict__ stats)
{
    constexpr int VEC = (MODE == 0) ? 4 : 8;
    const size_t nvec = (size_t)N_EDGES * 64 / VEC;
    size_t stride = (size_t)gridDim.x * 256;
    size_t g0 = (size_t)blockIdx.x * 256 + threadIdx.x;
    int c0 = (int)((g0 * VEC) & 63);
    float sum[VEC], sq[VEC];
    #pragma unroll
    for (int j = 0; j < VEC; ++j) { sum[j] = 0.0f; sq[j] = 0.0f; }

    for (size_t v = g0; v < nvec; v += stride) {
        float vals[VEC];
        if constexpr (MODE == 0) {
            float4 t = ((const float4*)h)[v];
            vals[0] = t.x; vals[1] = t.y; vals[2] = t.z; vals[3] = t.w;
        } else {
            uint4 t = ((const uint4*)h)[v];
            vals[0] = bf2f(t.x & 0xFFFF); vals[1] = bf2f(t.x >> 16);
            vals[2] = bf2f(t.y & 0xFFFF); vals[3] = bf2f(t.y >> 16);
            vals[4] = bf2f(t.z & 0xFFFF); vals[5] = bf2f(t.z >> 16);
            vals[6] = bf2f(t.w & 0xFFFF); vals[7] = bf2f(t.w >> 16);
        }
        #pragma unroll
        for (int j = 0; j < VEC; ++j) { sum[j] += vals[j]; sq[j] += vals[j] * vals[j]; }
    }
    __shared__ float ls[128];
    if (threadIdx.x < 128) ls[threadIdx.x] = 0.0f;
    __syncthreads();
    #pragma unroll
    for (int j = 0; j < VEC; ++j) {
        atomicAdd(&ls[c0 + j], sum[j]);
        atomicAdd(&ls[64 + c0 + j], sq[j]);
    }
    __syncthreads();
    if (threadIdx.x < 128)
        atomicAdd(&stats[S_PH + (blockIdx.x & (NPART-1)) * 128 + threadIdx.x],
                  ls[threadIdx.x]);
}

// ---- K3: reduce part_h -> mu/rs ----
__global__ void k_bnfin(float* stats) {
    int c = threadIdx.x;
    if (c < 64) {
        float s = 0.0f, q = 0.0f;
        #pragma unroll
        for (int p = 0; p < NPART; ++p) {
            s += stats[S_PH + p * 128 + c];
            q += stats[S_PH + p * 128 + 64 + c];
        }
        float m = s / (float)N_EDGES;
        float v = q / (float)N_EDGES - m * m;
        stats[c] = m;
        stats[64 + c] = rsqrtf(v + BN_EPS);
    }
}

// ---- K4: gate_lin per edge + gate batch stats + FUSED normalize/activate
//  write-back: h[e][c] <- silu(bn(h[e][c])) stored fp16 (mode1) / f32 (mode0).
//  k_aggr then needs zero transcendentals. ----
template<int MODE>
__global__ __launch_bounds__(256) void k_gate(
    void* __restrict__ h, const float* __restrict__ x,
    const float* __restrict__ pos, const int* __restrict__ ei,
    const float* __restrict__ W1, const float* __restrict__ b1,
    float* __restrict__ stats, const float* __restrict__ g1,
    const float* __restrict__ be1, const float* __restrict__ Wg,
    const float* __restrict__ bg, float* __restrict__ gate_lin, size_t h_cap)
{
    int e = blockIdx.x * 256 + threadIdx.x;
    float gl = bg[0];

    if constexpr (MODE == 2) {
        float hv[64];
        int jd;
        edge_gemm(e, x, pos, ei, W1, b1, hv, &jd);
        #pragma unroll
        for (int c = 0; c < 64; ++c) {
            float t = (hv[c] - stats[c]) * stats[64 + c] * g1[c] + be1[c];
            gl += silu(t) * Wg[c];
        }
    } else if constexpr (MODE == 0) {
        if ((size_t)(e + 1) * 256 <= h_cap) {
            float4* hq = (float4*)((char*)h + (size_t)e * 256);
            #pragma unroll
            for (int i = 0; i < 16; ++i) {
                float4 t = hq[i];
                float vv[4] = {t.x, t.y, t.z, t.w};
                float sv[4];
                #pragma unroll
                for (int j = 0; j < 4; ++j) {
                    int c = 4 * i + j;
                    float tt = (vv[j] - stats[c]) * stats[64 + c] * g1[c] + be1[c];
                    sv[j] = silu(tt);
                    gl += sv[j] * Wg[c];
                }
                hq[i] = make_float4(sv[0], sv[1], sv[2], sv[3]);  // write-back h'
            }
        }
    } else {
        if ((size_t)(e + 1) * 128 <= h_cap) {
            uint4* hq = (uint4*)((char*)h + (size_t)e * 128);
            #pragma unroll
            for (int j = 0; j < 8; ++j) {
                uint4 t = hq[j];
                float vv[8];
                vv[0] = bf2f(t.x & 0xFFFF); vv[1] = bf2f(t.x >> 16);
                vv[2] = bf2f(t.y & 0xFFFF); vv[3] = bf2f(t.y >> 16);
                vv[4] = bf2f(t.z & 0xFFFF); vv[5] = bf2f(t.z >> 16);
                vv[6] = bf2f(t.w & 0xFFFF); vv[7] = bf2f(t.w >> 16);
                unsigned pw[4];
                #pragma unroll
                for (int q = 0; q < 4; ++q) {
                    int c0 = 8 * j + 2 * q;
                    float t0 = (vv[2*q]   - stats[c0])   * stats[64 + c0]   * g1[c0]   + be1[c0];
                    float t1 = (vv[2*q+1] - stats[c0+1]) * stats[64 + c0+1] * g1[c0+1] + be1[c0+1];
                    float s0 = silu(t0), s1 = silu(t1);
                    gl += s0 * Wg[c0] + s1 * Wg[c0 + 1];
                    unsigned u0 = __half_as_ushort(__float2half(s0));
                    unsigned u1 = __half_as_ushort(__float2half(s1));
                    pw[q] = u0 | (u1 << 16);
                }
                hq[j] = make_uint4(pw[0], pw[1], pw[2], pw[3]);   // write-back h' fp16
            }
        }
    }
    gate_lin[e] = gl;

    float s1 = gl, s2 = gl * gl;
    #pragma unroll
    for (int off = 32; off >= 1; off >>= 1) {
        s1 += __shfl_xor(s1, off);
        s2 += __shfl_xor(s2, off);
    }
    __shared__ float red[8];
    int w = threadIdx.x >> 6, lane = threadIdx.x & 63;
    if (lane == 0) { red[w] = s1; red[4 + w] = s2; }
    __syncthreads();
    if (threadIdx.x == 0) {
        int slot = S_PG + (blockIdx.x & (NPART-1)) * 2;
        atomicAdd(&stats[slot], red[0] + red[1] + red[2] + red[3]);
        atomicAdd(&stats[slot + 1], red[4] + red[5] + red[6] + red[7]);
    }
}

// ---- K5: reduce part_g -> gmu/grs ----
__global__ void k_gfin(float* stats) {
    if (threadIdx.x == 0) {
        float s = 0.0f, q = 0.0f;
        for (int p = 0; p < NPART; ++p) {
            s += stats[S_PG + 2 * p];
            q += stats[S_PG + 2 * p + 1];
        }
        float m = s / (float)N_EDGES;
        float v = q / (float)N_EDGES - m * m;
        stats[128] = m;
        stats[129] = rsqrtf(v + BN_EPS);
    }
}

// ---- K_w: gate_lin[e] <- exp(silu(bn(gate_lin[e]))) — the softmax weight ----
__global__ __launch_bounds__(256) void k_w(float* __restrict__ gate_lin,
                                           const float* __restrict__ stats,
                                           const float* __restrict__ gg,
                                           const float* __restrict__ bgb)
{
    int e = blockIdx.x * 256 + threadIdx.x;
    float gl = gate_lin[e];
    float tg = (gl - stats[128]) * stats[129] * gg[0] + bgb[0];
    gate_lin[e] = fast_exp(silu(tg));
}

// ---- K6: single-block scan deg -> offs, cursor ----
__global__ __launch_bounds__(1024) void k_scan(const int* __restrict__ deg,
                                               int* __restrict__ offs,
                                               int* __restrict__ cursor)
{
    __shared__ int ps[1024];
    int t = threadIdx.x;
    const int CH = (N_NODES + 1023) / 1024;
    int lo = t * CH, hi = lo + CH;
    if (hi > N_NODES) hi = N_NODES;
    if (lo > N_NODES) lo = N_NODES;
    int s = 0;
    for (int i = lo; i < hi; ++i) s += deg[i];
    ps[t] = s;
    __syncthreads();
    for (int off = 1; off < 1024; off <<= 1) {
        int v = (t >= off) ? ps[t - off] : 0;
        __syncthreads();
        ps[t] += v;
        __syncthreads();
    }
    int run = (t == 0) ? 0 : ps[t - 1];
    for (int i = lo; i < hi; ++i) {
        offs[i] = run;
        cursor[i] = run;
        run += deg[i];
    }
    if (t == 1023) offs[N_NODES] = ps[1023];
}

// ---- K7: CSR fill ----
__global__ __launch_bounds__(256) void k_fill(const int* __restrict__ ei,
                                              int* __restrict__ cursor,
                                              int* __restrict__ elist)
{
    int e = blockIdx.x * 256 + threadIdx.x;
    int js = ei[e];
    int d = ei[N_EDGES + e];
    if ((unsigned)js >= (unsigned)N_NODES || (unsigned)d >= (unsigned)N_NODES) return;
    int p = atomicAdd(&cursor[d], 1);
    if ((unsigned)p < (unsigned)N_EDGES) elist[p] = e;
}

// ---- K8: wave per node, lane = channel. Lean loop: h' and w are precomputed,
//  so per edge = 2 scalar loads + 1 coalesced row + 2 FMA. 1-deep prefetch. ----
template<int MODE>
__device__ __forceinline__ void aggr_body(
    const void* __restrict__ h, size_t h_cap, const float* __restrict__ wgt,
    const int* __restrict__ offs, const int* __restrict__ elist,
    const int* __restrict__ ei, const float* __restrict__ x,
    const float* __restrict__ pos, const float* __restrict__ b1,
    const float* W1s, const float* __restrict__ stats,
    const float* __restrict__ g1, const float* __restrict__ be1,
    float* __restrict__ out)
{
    int wid = (blockIdx.x * 256 + threadIdx.x) >> 6;
    int lane = threadIdx.x & 63;
    if (wid >= N_NODES) return;

    int lo = offs[wid], hi = offs[wid + 1];
    float accv = 0.0f, wsum = 0.0f;

    if constexpr (MODE == 2) {
        float mu = stats[lane], rs = stats[64 + lane];
        float ga = g1[lane], bb = be1[lane];
        float b1v = b1[lane];
        float pim = (lane >= IN_CH) ? pos[wid * 3 + (lane - IN_CH)] : 0.0f;
        for (int i = lo; i < hi; ++i) {
            int e = elist[i];
            float w = wgt[e];
            int js = ei[e];
            if ((unsigned)js >= (unsigned)N_NODES) continue;
            float fl = (lane < IN_CH) ? x[(size_t)js * IN_CH + lane]
                                      : pos[js * 3 + (lane - IN_CH)] - pim;
            float a = b1v;
            #pragma unroll
            for (int k = 0; k < 64; ++k) a += __shfl(fl, k) * W1s[k * 64 + lane];
            float tn = (a - mu) * rs * ga + bb;
            accv += w * silu(tn);
            wsum += w;
        }
    } else {
        auto load_h = [&](int e) -> float {
            if constexpr (MODE == 0) {
                if ((size_t)(e + 1) * 256 > h_cap) return 0.0f;
                return ((const float*)h)[(size_t)e * 64 + lane];
            } else {
                if ((size_t)(e + 1) * 128 > h_cap) return 0.0f;
                return __half2float(__ushort_as_half(
                    ((const unsigned short*)h)[(size_t)e * 64 + lane]));
            }
        };
        if (lo < hi) {
            int e = elist[lo];
            float w = wgt[e];
            float hval = load_h(e);
            for (int i = lo; i < hi; ++i) {
                int en = 0; float wn = 0.0f, hn = 0.0f;
                if (i + 1 < hi) {            // prefetch next edge while computing
                    en = elist[i + 1];
                    wn = wgt[en];
                    hn = load_h(en);
                }
                accv += w * hval;
                wsum += w;
                e = en; w = wn; hval = hn;
            }
        }
    }
    out[(size_t)wid * 64 + lane] = accv / (wsum + 1e-16f);
}

template<int MODE>
__global__ __launch_bounds__(256) void k_aggr(
    const void* __restrict__ h, size_t h_cap, const float* __restrict__ wgt,
    const int* __restrict__ offs, const int* __restrict__ elist,
    const int* __restrict__ ei, const float* __restrict__ x,
    const float* __restrict__ pos, const float* __restrict__ b1,
    const float* __restrict__ W1, const float* __restrict__ stats,
    const float* __restrict__ g1, const float* __restrict__ be1,
    float* __restrict__ out)
{
    if constexpr (MODE == 2) {
        __shared__ float W1s[4096];
        for (int i = threadIdx.x; i < 4096; i += 256) W1s[i] = W1[i];
        __syncthreads();
        aggr_body<2>(h, h_cap, wgt, offs, elist, ei, x, pos, b1, W1s,
                     stats, g1, be1, out);
    } else {
        aggr_body<MODE>(h, h_cap, wgt, offs, elist, ei, x, pos, b1, nullptr,
                        stats, g1, be1, out);
    }
}

extern "C" void kernel_launch(void* const* d_in, const int* in_sizes, int n_in,
                              void* d_out, int out_size, void* d_ws, size_t ws_size,
                              hipStream_t stream)
{
    const float* x   = (const float*)d_in[0];
    const float* pos = (const float*)d_in[1];
    const int*   ei  = (const int*)d_in[2];
    const float* W1  = (const float*)d_in[3];
    const float* b1  = (const float*)d_in[4];
    const float* g1  = (const float*)d_in[5];
    const float* be1 = (const float*)d_in[6];
    const float* Wg  = (const float*)d_in[7];
    const float* bg  = (const float*)d_in[8];
    const float* gg  = (const float*)d_in[9];
    const float* bgb = (const float*)d_in[10];
    float* out = (float*)d_out;

    char* base = (char*)d_ws;
    size_t off = 0;
    auto alloc = [&](size_t bytes) {
        size_t o = off;
        off = (off + bytes + 255) & ~(size_t)255;
        return o;
    };
    float* stats    = (float*)(base + alloc(S_TOT * 4));
    int*   deg      = (int*)(base + alloc((size_t)N_NODES * 4));
    int*   offs     = (int*)(base + alloc((size_t)(N_NODES + 1) * 4));
    int*   cursor   = (int*)(base + alloc((size_t)N_NODES * 4));
    int*   elist    = (int*)(base + alloc((size_t)N_EDGES * 4));
    float* gate_lin = (float*)(base + alloc((size_t)N_EDGES * 4));
    short* wfrag    = (short*)(base + alloc(8192 * 2));     // W1 bf16 hi/lo fragments
    if (ws_size < off) return;
    void*  h     = (void*)(base + off);
    size_t h_cap = ws_size - off;

    const int mode = (h_cap >= (size_t)N_EDGES * 256) ? 0
                   : (h_cap >= (size_t)N_EDGES * 128) ? 1 : 2;

    const int EB  = N_EDGES / 256;           // 6250 exact
    const int EB2 = N_EDGES / 128;           // 12500 exact (legacy k_edge)
    const int EBM = N_EDGES / 64;            // 25000 exact (mfma k_edge)
    const int NB  = (N_NODES + 255) / 256;   // 391
    const int AB  = (N_NODES + 3) / 4;       // 25001

    hipLaunchKernelGGL(k_init, dim3(NB), dim3(256), 0, stream, stats, deg);

    if (mode == 0) {
        hipLaunchKernelGGL(k_edge<0>, dim3(EB2), dim3(128), 0, stream,
                           x, pos, ei, W1, b1, stats, deg, h, h_cap);
        hipLaunchKernelGGL(k_stats<0>, dim3(1024), dim3(256), 0, stream, h, stats);
        hipLaunchKernelGGL(k_bnfin, dim3(1), dim3(64), 0, stream, stats);
        hipLaunchKernelGGL(k_gate<0>, dim3(EB), dim3(256), 0, stream,
                           h, x, pos, ei, W1, b1, stats, g1, be1, Wg, bg, gate_lin, h_cap);
    } else if (mode == 1) {
        hipLaunchKernelGGL(k_prep, dim3(16), dim3(256), 0, stream, W1, wfrag);
        hipLaunchKernelGGL(k_edge_mfma, dim3(EBM), dim3(256), 0, stream,
                           x, pos, ei, wfrag, b1, stats, deg, h, h_cap);
        hipLaunchKernelGGL(k_bnfin, dim3(1), dim3(64), 0, stream, stats);
        hipLaunchKernelGGL(k_gate<1>, dim3(EB), dim3(256), 0, stream,
                           h, x, pos, ei, W1, b1, stats, g1, be1, Wg, bg, gate_lin, h_cap);
    } else {
        hipLaunchKernelGGL(k_edge<2>, dim3(EB2), dim3(128), 0, stream,
                           x, pos, ei, W1, b1, stats, deg, h, h_cap);
        hipLaunchKernelGGL(k_bnfin, dim3(1), dim3(64), 0, stream, stats);
        hipLaunchKernelGGL(k_gate<2>, dim3(EB), dim3(256), 0, stream,
                           h, x, pos, ei, W1, b1, stats, g1, be1, Wg, bg, gate_lin, h_cap);
    }

    hipLaunchKernelGGL(k_gfin, dim3(1), dim3(64), 0, stream, stats);
    hipLaunchKernelGGL(k_w,    dim3(EB), dim3(256), 0, stream, gate_lin, stats, gg, bgb);
    hipLaunchKernelGGL(k_scan, dim3(1), dim3(1024), 0, stream, deg, offs, cursor);
    hipLaunchKernelGGL(k_fill, dim3(EB), dim3(256), 0, stream, ei, cursor, elist);

    if (mode == 0) {
        hipLaunchKernelGGL(k_aggr<0>, dim3(AB), dim3(256), 0, stream,
                           h, h_cap, gate_lin, offs, elist, ei, x, pos, b1, W1,
                           stats, g1, be1, out);
    } else if (mode == 1) {
        hipLaunchKernelGGL(k_aggr<1>, dim3(AB), dim3(256), 0, stream,
                           h, h_cap, gate_lin, offs, elist, ei, x, pos, b1, W1,
                           stats, g1, be1, out);
    } else {
        hipLaunchKernelGGL(k_aggr<2>, dim3(AB), dim3(256), 0, stream,
                           h, h_cap, gate_lin, offs, elist, ei, x, pos, b1, W1,
                           stats, g1, be1, out);
    }
}

// Round 12
// 967.164 us; speedup vs baseline: 2.2699x; 1.0186x over previous
//
#include <hip/hip_runtime.h>
#include <hip/hip_bf16.h>
#include <hip/hip_fp16.h>
#include <math.h>

// Problem constants (fixed by reference)
constexpr int N_NODES = 100000;
constexpr int N_EDGES = 1600000;
constexpr int IN_CH   = 61;
constexpr float BN_EPS = 1e-5f;
constexpr int NPART   = 32;   // atomic spread slots

// stats layout (floats), total 4352:
//  [0..63] mu_h   [64..127] rs_h   [128] gmu [129] grs
//  [192..) part_h: slot s -> [192+s*128+c]=sum_c, [+64+c]=sumsq_c
//  [4288..) part_g: slot s -> [4288+2s]=sum, [+1]=sumsq
constexpr int S_PH = 192;
constexpr int S_PG = 192 + NPART * 128;      // 4288
constexpr int S_TOT = S_PG + NPART * 2;      // 4352

typedef float f32x4 __attribute__((ext_vector_type(4)));
typedef short s16x8 __attribute__((ext_vector_type(8)));

// Fast transcendentals: native v_exp_f32 + v_rcp_f32 (~1 ulp; tolerance budget is
// dominated by bf16 h quantization at 0.0156, so this is free accuracy-wise).
__device__ __forceinline__ float fast_exp(float x) { return __expf(x); }
__device__ __forceinline__ float silu(float x) {
    return x * __builtin_amdgcn_rcpf(1.0f + __expf(-x));
}

__device__ __forceinline__ float bf2f(unsigned v) { return __uint_as_float(v << 16); }
__device__ __forceinline__ unsigned f2bf(float f) {
    unsigned u = __float_as_uint(f);
    return (u + 0x7FFFu + ((u >> 16) & 1u)) >> 16;   // RNE
}

// Full-64 matvec helper — used only by MODE 2 / mode 0 legacy paths.
__device__ __forceinline__ bool edge_gemm(
    int e, const float* __restrict__ x, const float* __restrict__ pos,
    const int* __restrict__ ei, const float* __restrict__ W1,
    const float* __restrict__ b1, float* acc, int* jd_out)
{
    int js = ei[e];
    int jd = ei[N_EDGES + e];
    *jd_out = jd;
    bool valid = ((unsigned)js < (unsigned)N_NODES) && ((unsigned)jd < (unsigned)N_NODES);
    if (!valid) {
        #pragma unroll
        for (int c = 0; c < 64; ++c) acc[c] = 0.0f;
        return false;
    }
    #pragma unroll
    for (int c = 0; c < 64; ++c) acc[c] = b1[c];
    const float* xr = x + (size_t)js * IN_CH;
    #pragma unroll 4
    for (int k = 0; k < IN_CH; ++k) {
        float fk = xr[k];
        #pragma unroll
        for (int c = 0; c < 64; ++c) acc[c] += fk * W1[k * 64 + c];
    }
    #pragma unroll
    for (int j = 0; j < 3; ++j) {
        float fk = pos[js * 3 + j] - pos[jd * 3 + j];
        #pragma unroll
        for (int c = 0; c < 64; ++c) acc[c] += fk * W1[(IN_CH + j) * 64 + c];
    }
    return true;
}

// ---- K0: init stats + deg ----
__global__ __launch_bounds__(256) void k_init(float* stats, int* deg) {
    int i = blockIdx.x * 256 + threadIdx.x;
    if (i < S_TOT) stats[i] = 0.0f;
    if (i < N_NODES) deg[i] = 0;
}

// ---- K_prep: W1 -> bf16 hi/lo in MFMA B-fragment order (runs once per launch). ----
__global__ __launch_bounds__(256) void k_prep(const float* __restrict__ W1,
                                              short* __restrict__ wf)
{
    int i = blockIdx.x * 256 + threadIdx.x;   // 16 blocks x 256 = 4096 slots
    int j    = i & 7;
    int lane = (i >> 3) & 63;
    int kc   = (i >> 9) & 1;
    int ct   = i >> 10;
    int c = ct * 16 + (lane & 15);
    int k = kc * 32 + (lane >> 4) * 8 + j;
    float v = W1[k * 64 + c];
    unsigned hi = f2bf(v);
    unsigned lo = f2bf(v - bf2f(hi));
    wf[i] = (short)hi;
    wf[4096 + i] = (short)lo;
}

// ---- K1 v5 (mode 1): MFMA edge GEMM, 64 edges/block, 4 waves. (unchanged) ----
__global__ __launch_bounds__(256) void k_edge_mfma(
    const float* __restrict__ x, const float* __restrict__ pos,
    const int* __restrict__ ei, const short* __restrict__ wf,
    const float* __restrict__ b1, float* __restrict__ stats,
    int* __restrict__ deg, void* __restrict__ h, size_t h_cap)
{
    __shared__ __align__(16) short fsh[64][72];   // f hi (bf16), pad 72
    __shared__ __align__(16) short fsl[64][72];   // f lo
    __shared__ float lsum[128];                   // fused stats partials

    const int tid  = threadIdx.x;
    const int w    = tid >> 6, lane = tid & 63;
    const int e0   = blockIdx.x * 64;             // grid exact: E/64

    if (tid < 128) lsum[tid] = 0.0f;

    int js_l = 0, jd_l = 0;
    if (lane < 16) {
        int e = e0 + w * 16 + lane;
        js_l = ei[e];
        jd_l = ei[N_EDGES + e];
        if ((unsigned)js_l >= (unsigned)N_NODES) js_l = 0;
        if ((unsigned)jd_l >= (unsigned)N_NODES) jd_l = 0;
        atomicAdd(&deg[jd_l], 1);
    }

    #pragma unroll 4
    for (int j = 0; j < 16; ++j) {
        int js = __shfl(js_l, j);
        int jd = __shfl(jd_l, j);
        int r  = w * 16 + j;
        float v;
        if (lane < IN_CH) v = x[(size_t)js * IN_CH + lane];
        else              v = pos[js * 3 + (lane - IN_CH)] - pos[jd * 3 + (lane - IN_CH)];
        unsigned hi = f2bf(v);
        unsigned lo = f2bf(v - bf2f(hi));
        fsh[r][lane] = (short)hi;
        fsl[r][lane] = (short)lo;
    }
    __syncthreads();

    const int r = lane & 15, g = lane >> 4;
    const int arow = w * 16 + r;
    s16x8 ah0 = *(const s16x8*)&fsh[arow][g * 8];
    s16x8 ah1 = *(const s16x8*)&fsh[arow][32 + g * 8];
    s16x8 al0 = *(const s16x8*)&fsl[arow][g * 8];
    s16x8 al1 = *(const s16x8*)&fsl[arow][32 + g * 8];

    const bool do_h = ((size_t)(e0 + 64) * 128 <= h_cap);
    unsigned short* hp = (unsigned short*)h;

    #pragma unroll
    for (int ct = 0; ct < 4; ++ct) {
        int c = ct * 16 + r;
        s16x8 bh0 = *(const s16x8*)&wf[((ct * 2 + 0) * 64 + lane) * 8];
        s16x8 bh1 = *(const s16x8*)&wf[((ct * 2 + 1) * 64 + lane) * 8];
        s16x8 bl0 = *(const s16x8*)&wf[4096 + ((ct * 2 + 0) * 64 + lane) * 8];
        s16x8 bl1 = *(const s16x8*)&wf[4096 + ((ct * 2 + 1) * 64 + lane) * 8];
        f32x4 acc = {0.0f, 0.0f, 0.0f, 0.0f};
        acc = __builtin_amdgcn_mfma_f32_16x16x32_bf16(al0, bh0, acc, 0, 0, 0);
        acc = __builtin_amdgcn_mfma_f32_16x16x32_bf16(al1, bh1, acc, 0, 0, 0);
        acc = __builtin_amdgcn_mfma_f32_16x16x32_bf16(ah0, bl0, acc, 0, 0, 0);
        acc = __builtin_amdgcn_mfma_f32_16x16x32_bf16(ah1, bl1, acc, 0, 0, 0);
        acc = __builtin_amdgcn_mfma_f32_16x16x32_bf16(ah0, bh0, acc, 0, 0, 0);
        acc = __builtin_amdgcn_mfma_f32_16x16x32_bf16(ah1, bh1, acc, 0, 0, 0);
        float bias = b1[c];
        float s = 0.0f, q = 0.0f;
        #pragma unroll
        for (int i = 0; i < 4; ++i) {
            unsigned hb = f2bf(acc[i] + bias);
            float v = bf2f(hb);               // stats from bf16-rounded h
            s += v; q += v * v;
            if (do_h) {
                int row = w * 16 + g * 4 + i;
                hp[(size_t)(e0 + row) * 64 + c] = (unsigned short)hb;
            }
        }
        s += __shfl_xor(s, 16); s += __shfl_xor(s, 32);
        q += __shfl_xor(q, 16); q += __shfl_xor(q, 32);
        if (g == 0) {
            atomicAdd(&lsum[c], s);
            atomicAdd(&lsum[64 + c], q);
        }
    }
    __syncthreads();
    if (tid < 128)
        atomicAdd(&stats[S_PH + (blockIdx.x & (NPART - 1)) * 128 + tid], lsum[tid]);
}

// ---- K1 legacy (modes 0/2): LDS-staged scalar path ----
template<int MODE>
__global__ __launch_bounds__(128) void k_edge(
    const float* __restrict__ x, const float* __restrict__ pos,
    const int* __restrict__ ei, const float* __restrict__ W1,
    const float* __restrict__ b1, float* __restrict__ stats,
    int* __restrict__ deg, void* __restrict__ h, size_t h_cap)
{
    constexpr int EPB = 128;
    __shared__ float fs[EPB][65];
    __shared__ float ls[128];

    const int tid  = threadIdx.x;
    const int wave = tid >> 6, lane = tid & 63;
    const int eb   = blockIdx.x * EPB;
    const int r0   = wave * 64;

    const int eg = eb + r0 + lane;
    int js_l = ei[eg];
    int jd_l = ei[N_EDGES + eg];
    bool valid = ((unsigned)js_l < (unsigned)N_NODES) &&
                 ((unsigned)jd_l < (unsigned)N_NODES);
    if (valid) atomicAdd(&deg[jd_l], 1);

    if constexpr (MODE == 2) {
        if (tid < 128) ls[tid] = 0.0f;
    }

    for (int j = 0; j < 64; ++j) {
        int js = __shfl(js_l, j);
        int jd = __shfl(jd_l, j);
        int ok = __shfl((int)valid, j);
        int r = r0 + j;
        if (lane < IN_CH) {
            fs[r][lane] = ok ? x[(size_t)js * IN_CH + lane] : 0.0f;
        } else {
            int d = lane - IN_CH;
            fs[r][lane] = ok ? (pos[js * 3 + d] - pos[jd * 3 + d]) : 0.0f;
        }
    }
    __syncthreads();

    #pragma unroll 1
    for (int half = 0; half < 2; ++half) {
        const int base = half * 32;
        float acc[32];
        #pragma unroll
        for (int c = 0; c < 32; ++c) acc[c] = valid ? b1[base + c] : 0.0f;
        if (valid) {
            #pragma unroll 4
            for (int k = 0; k < 64; ++k) {
                float fk = fs[tid][k];
                #pragma unroll
                for (int c = 0; c < 32; ++c)
                    acc[c] += fk * W1[k * 64 + base + c];
            }
        }
        if constexpr (MODE == 0) {
            if ((size_t)(eb + tid + 1) * 256 <= h_cap) {
                float4* hq = (float4*)((char*)h + (size_t)(eb + tid) * 256
                                       + (size_t)base * 4);
                #pragma unroll
                for (int i = 0; i < 8; ++i)
                    hq[i] = make_float4(acc[4*i], acc[4*i+1], acc[4*i+2], acc[4*i+3]);
            }
        } else {
            #pragma unroll
            for (int c = 0; c < 32; ++c) {
                atomicAdd(&ls[base + c], acc[c]);
                atomicAdd(&ls[64 + base + c], acc[c] * acc[c]);
            }
        }
    }

    if constexpr (MODE == 2) {
        __syncthreads();
        if (tid < 128)
            atomicAdd(&stats[S_PH + (blockIdx.x & (NPART-1)) * 128 + tid], ls[tid]);
    }
}

// ---- K2: per-channel sum/sumsq streaming over h (mode 0 only) ----
template<int MODE>
__global__ __launch_bounds__(256) void k_stats(const void* __restrict__ h,
                                               float* __restrict__ stats)
{
    constexpr int VEC = (MODE == 0) ? 4 : 8;
    const size_t nvec = (size_t)N_EDGES * 64 / VEC;
    size_t stride = (size_t)gridDim.x * 256;
    size_t g0 = (size_t)blockIdx.x * 256 + threadIdx.x;
    int c0 = (int)((g0 * VEC) & 63);
    float sum[VEC], sq[VEC];
    #pragma unroll
    for (int j = 0; j < VEC; ++j) { sum[j] = 0.0f; sq[j] = 0.0f; }

    for (size_t v = g0; v < nvec; v += stride) {
        float vals[VEC];
        if constexpr (MODE == 0) {
            float4 t = ((const float4*)h)[v];
            vals[0] = t.x; vals[1] = t.y; vals[2] = t.z; vals[3] = t.w;
        } else {
            uint4 t = ((const uint4*)h)[v];
            vals[0] = bf2f(t.x & 0xFFFF); vals[1] = bf2f(t.x >> 16);
            vals[2] = bf2f(t.y & 0xFFFF); vals[3] = bf2f(t.y >> 16);
            vals[4] = bf2f(t.z & 0xFFFF); vals[5] = bf2f(t.z >> 16);
            vals[6] = bf2f(t.w & 0xFFFF); vals[7] = bf2f(t.w >> 16);
        }
        #pragma unroll
        for (int j = 0; j < VEC; ++j) { sum[j] += vals[j]; sq[j] += vals[j] * vals[j]; }
    }
    __shared__ float ls[128];
    if (threadIdx.x < 128) ls[threadIdx.x] = 0.0f;
    __syncthreads();
    #pragma unroll
    for (int j = 0; j < VEC; ++j) {
        atomicAdd(&ls[c0 + j], sum[j]);
        atomicAdd(&ls[64 + c0 + j], sq[j]);
    }
    __syncthreads();
    if (threadIdx.x < 128)
        atomicAdd(&stats[S_PH + (blockIdx.x & (NPART-1)) * 128 + threadIdx.x],
                  ls[threadIdx.x]);
}

// ---- K3: reduce part_h -> mu/rs ----
__global__ void k_bnfin(float* stats) {
    int c = threadIdx.x;
    if (c < 64) {
        float s = 0.0f, q = 0.0f;
        #pragma unroll
        for (int p = 0; p < NPART; ++p) {
            s += stats[S_PH + p * 128 + c];
            q += stats[S_PH + p * 128 + 64 + c];
        }
        float m = s / (float)N_EDGES;
        float v = q / (float)N_EDGES - m * m;
        stats[c] = m;
        stats[64 + c] = rsqrtf(v + BN_EPS);
    }
}

// ---- K4: gate_lin per edge + gate batch stats (READ-ONLY h — no write-back;
//  k_aggr applies bn+silu itself. Saves a 205MB write pass.) ----
template<int MODE>
__global__ __launch_bounds__(256) void k_gate(
    const void* __restrict__ h, const float* __restrict__ x,
    const float* __restrict__ pos, const int* __restrict__ ei,
    const float* __restrict__ W1, const float* __restrict__ b1,
    float* __restrict__ stats, const float* __restrict__ g1,
    const float* __restrict__ be1, const float* __restrict__ Wg,
    const float* __restrict__ bg, float* __restrict__ gate_lin, size_t h_cap)
{
    int e = blockIdx.x * 256 + threadIdx.x;
    float gl = bg[0];

    if constexpr (MODE == 2) {
        float hv[64];
        int jd;
        edge_gemm(e, x, pos, ei, W1, b1, hv, &jd);
        #pragma unroll
        for (int c = 0; c < 64; ++c) {
            float t = (hv[c] - stats[c]) * stats[64 + c] * g1[c] + be1[c];
            gl += silu(t) * Wg[c];
        }
    } else if constexpr (MODE == 0) {
        if ((size_t)(e + 1) * 256 <= h_cap) {
            const float4* hq = (const float4*)((const char*)h + (size_t)e * 256);
            #pragma unroll
            for (int i = 0; i < 16; ++i) {
                float4 t = hq[i];
                float vv[4] = {t.x, t.y, t.z, t.w};
                #pragma unroll
                for (int j = 0; j < 4; ++j) {
                    int c = 4 * i + j;
                    float tt = (vv[j] - stats[c]) * stats[64 + c] * g1[c] + be1[c];
                    gl += silu(tt) * Wg[c];
                }
            }
        }
    } else {
        if ((size_t)(e + 1) * 128 <= h_cap) {
            const uint4* hq = (const uint4*)((const char*)h + (size_t)e * 128);
            #pragma unroll
            for (int j = 0; j < 8; ++j) {
                uint4 t = hq[j];
                float vv[8];
                vv[0] = bf2f(t.x & 0xFFFF); vv[1] = bf2f(t.x >> 16);
                vv[2] = bf2f(t.y & 0xFFFF); vv[3] = bf2f(t.y >> 16);
                vv[4] = bf2f(t.z & 0xFFFF); vv[5] = bf2f(t.z >> 16);
                vv[6] = bf2f(t.w & 0xFFFF); vv[7] = bf2f(t.w >> 16);
                #pragma unroll
                for (int q = 0; q < 8; ++q) {
                    int c = 8 * j + q;
                    float tt = (vv[q] - stats[c]) * stats[64 + c] * g1[c] + be1[c];
                    gl += silu(tt) * Wg[c];
                }
            }
        }
    }
    gate_lin[e] = gl;

    float s1 = gl, s2 = gl * gl;
    #pragma unroll
    for (int off = 32; off >= 1; off >>= 1) {
        s1 += __shfl_xor(s1, off);
        s2 += __shfl_xor(s2, off);
    }
    __shared__ float red[8];
    int w = threadIdx.x >> 6, lane = threadIdx.x & 63;
    if (lane == 0) { red[w] = s1; red[4 + w] = s2; }
    __syncthreads();
    if (threadIdx.x == 0) {
        int slot = S_PG + (blockIdx.x & (NPART-1)) * 2;
        atomicAdd(&stats[slot], red[0] + red[1] + red[2] + red[3]);
        atomicAdd(&stats[slot + 1], red[4] + red[5] + red[6] + red[7]);
    }
}

// ---- K5: reduce part_g -> gmu/grs ----
__global__ void k_gfin(float* stats) {
    if (threadIdx.x == 0) {
        float s = 0.0f, q = 0.0f;
        for (int p = 0; p < NPART; ++p) {
            s += stats[S_PG + 2 * p];
            q += stats[S_PG + 2 * p + 1];
        }
        float m = s / (float)N_EDGES;
        float v = q / (float)N_EDGES - m * m;
        stats[128] = m;
        stats[129] = rsqrtf(v + BN_EPS);
    }
}

// ---- K6: single-block scan deg -> offs, cursor ----
__global__ __launch_bounds__(1024) void k_scan(const int* __restrict__ deg,
                                               int* __restrict__ offs,
                                               int* __restrict__ cursor)
{
    __shared__ int ps[1024];
    int t = threadIdx.x;
    const int CH = (N_NODES + 1023) / 1024;
    int lo = t * CH, hi = lo + CH;
    if (hi > N_NODES) hi = N_NODES;
    if (lo > N_NODES) lo = N_NODES;
    int s = 0;
    for (int i = lo; i < hi; ++i) s += deg[i];
    ps[t] = s;
    __syncthreads();
    for (int off = 1; off < 1024; off <<= 1) {
        int v = (t >= off) ? ps[t - off] : 0;
        __syncthreads();
        ps[t] += v;
        __syncthreads();
    }
    int run = (t == 0) ? 0 : ps[t - 1];
    for (int i = lo; i < hi; ++i) {
        offs[i] = run;
        cursor[i] = run;
        run += deg[i];
    }
    if (t == 1023) offs[N_NODES] = ps[1023];
}

// ---- K7: CSR fill + FUSED softmax-weight transform:
//  gate_lin[e] <- exp(silu(bn_g(gate_lin[e]))) in place (each e visited once). ----
__global__ __launch_bounds__(256) void k_fill(const int* __restrict__ ei,
                                              int* __restrict__ cursor,
                                              int* __restrict__ elist,
                                              float* __restrict__ gate_lin,
                                              const float* __restrict__ stats,
                                              const float* __restrict__ gg,
                                              const float* __restrict__ bgb)
{
    int e = blockIdx.x * 256 + threadIdx.x;
    float gl = gate_lin[e];
    float tg = (gl - stats[128]) * stats[129] * gg[0] + bgb[0];
    gate_lin[e] = fast_exp(silu(tg));

    int js = ei[e];
    int d = ei[N_EDGES + e];
    if ((unsigned)js >= (unsigned)N_NODES || (unsigned)d >= (unsigned)N_NODES) return;
    int p = atomicAdd(&cursor[d], 1);
    if ((unsigned)p < (unsigned)N_EDGES) elist[p] = e;
}

// ---- K8: wave per node, lane = channel. Reads original h; applies bn+silu
//  in-loop (transcendentals are ~free; bytes are not). 1-deep prefetch. ----
template<int MODE>
__device__ __forceinline__ void aggr_body(
    const void* __restrict__ h, size_t h_cap, const float* __restrict__ wgt,
    const int* __restrict__ offs, const int* __restrict__ elist,
    const int* __restrict__ ei, const float* __restrict__ x,
    const float* __restrict__ pos, const float* __restrict__ b1,
    const float* W1s, const float* __restrict__ stats,
    const float* __restrict__ g1, const float* __restrict__ be1,
    float* __restrict__ out)
{
    int wid = (blockIdx.x * 256 + threadIdx.x) >> 6;
    int lane = threadIdx.x & 63;
    if (wid >= N_NODES) return;

    float mu = stats[lane], rs = stats[64 + lane];
    float ga = g1[lane], bb = be1[lane];

    int lo = offs[wid], hi = offs[wid + 1];
    float accv = 0.0f, wsum = 0.0f;

    if constexpr (MODE == 2) {
        float b1v = b1[lane];
        float pim = (lane >= IN_CH) ? pos[wid * 3 + (lane - IN_CH)] : 0.0f;
        for (int i = lo; i < hi; ++i) {
            int e = elist[i];
            float w = wgt[e];
            int js = ei[e];
            if ((unsigned)js >= (unsigned)N_NODES) continue;
            float fl = (lane < IN_CH) ? x[(size_t)js * IN_CH + lane]
                                      : pos[js * 3 + (lane - IN_CH)] - pim;
            float a = b1v;
            #pragma unroll
            for (int k = 0; k < 64; ++k) a += __shfl(fl, k) * W1s[k * 64 + lane];
            float tn = (a - mu) * rs * ga + bb;
            accv += w * silu(tn);
            wsum += w;
        }
    } else {
        auto load_h = [&](int e) -> float {
            if constexpr (MODE == 0) {
                if ((size_t)(e + 1) * 256 > h_cap) return 0.0f;
                return ((const float*)h)[(size_t)e * 64 + lane];
            } else {
                if ((size_t)(e + 1) * 128 > h_cap) return 0.0f;
                return bf2f(((const unsigned short*)h)[(size_t)e * 64 + lane]);
            }
        };
        if (lo < hi) {
            int e = elist[lo];
            float w = wgt[e];
            float hval = load_h(e);
            for (int i = lo; i < hi; ++i) {
                int en = 0; float wn = 0.0f, hn = 0.0f;
                if (i + 1 < hi) {            // prefetch next edge while computing
                    en = elist[i + 1];
                    wn = wgt[en];
                    hn = load_h(en);
                }
                float tn = (hval - mu) * rs * ga + bb;
                accv += w * silu(tn);
                wsum += w;
                e = en; w = wn; hval = hn;
            }
        }
    }
    out[(size_t)wid * 64 + lane] = accv / (wsum + 1e-16f);
}

template<int MODE>
__global__ __launch_bounds__(256) void k_aggr(
    const void* __restrict__ h, size_t h_cap, const float* __restrict__ wgt,
    const int* __restrict__ offs, const int* __restrict__ elist,
    const int* __restrict__ ei, const float* __restrict__ x,
    const float* __restrict__ pos, const float* __restrict__ b1,
    const float* __restrict__ W1, const float* __restrict__ stats,
    const float* __restrict__ g1, const float* __restrict__ be1,
    float* __restrict__ out)
{
    if constexpr (MODE == 2) {
        __shared__ float W1s[4096];
        for (int i = threadIdx.x; i < 4096; i += 256) W1s[i] = W1[i];
        __syncthreads();
        aggr_body<2>(h, h_cap, wgt, offs, elist, ei, x, pos, b1, W1s,
                     stats, g1, be1, out);
    } else {
        aggr_body<MODE>(h, h_cap, wgt, offs, elist, ei, x, pos, b1, nullptr,
                        stats, g1, be1, out);
    }
}

extern "C" void kernel_launch(void* const* d_in, const int* in_sizes, int n_in,
                              void* d_out, int out_size, void* d_ws, size_t ws_size,
                              hipStream_t stream)
{
    const float* x   = (const float*)d_in[0];
    const float* pos = (const float*)d_in[1];
    const int*   ei  = (const int*)d_in[2];
    const float* W1  = (const float*)d_in[3];
    const float* b1  = (const float*)d_in[4];
    const float* g1  = (const float*)d_in[5];
    const float* be1 = (const float*)d_in[6];
    const float* Wg  = (const float*)d_in[7];
    const float* bg  = (const float*)d_in[8];
    const float* gg  = (const float*)d_in[9];
    const float* bgb = (const float*)d_in[10];
    float* out = (float*)d_out;

    char* base = (char*)d_ws;
    size_t off = 0;
    auto alloc = [&](size_t bytes) {
        size_t o = off;
        off = (off + bytes + 255) & ~(size_t)255;
        return o;
    };
    float* stats    = (float*)(base + alloc(S_TOT * 4));
    int*   deg      = (int*)(base + alloc((size_t)N_NODES * 4));
    int*   offs     = (int*)(base + alloc((size_t)(N_NODES + 1) * 4));
    int*   cursor   = (int*)(base + alloc((size_t)N_NODES * 4));
    int*   elist    = (int*)(base + alloc((size_t)N_EDGES * 4));
    float* gate_lin = (float*)(base + alloc((size_t)N_EDGES * 4));
    short* wfrag    = (short*)(base + alloc(8192 * 2));     // W1 bf16 hi/lo fragments
    if (ws_size < off) return;
    void*  h     = (void*)(base + off);
    size_t h_cap = ws_size - off;

    const int mode = (h_cap >= (size_t)N_EDGES * 256) ? 0
                   : (h_cap >= (size_t)N_EDGES * 128) ? 1 : 2;

    const int EB  = N_EDGES / 256;           // 6250 exact
    const int EB2 = N_EDGES / 128;           // 12500 exact (legacy k_edge)
    const int EBM = N_EDGES / 64;            // 25000 exact (mfma k_edge)
    const int NB  = (N_NODES + 255) / 256;   // 391
    const int AB  = (N_NODES + 3) / 4;       // 25001

    hipLaunchKernelGGL(k_init, dim3(NB), dim3(256), 0, stream, stats, deg);

    if (mode == 0) {
        hipLaunchKernelGGL(k_edge<0>, dim3(EB2), dim3(128), 0, stream,
                           x, pos, ei, W1, b1, stats, deg, h, h_cap);
        hipLaunchKernelGGL(k_stats<0>, dim3(1024), dim3(256), 0, stream, h, stats);
        hipLaunchKernelGGL(k_bnfin, dim3(1), dim3(64), 0, stream, stats);
        hipLaunchKernelGGL(k_gate<0>, dim3(EB), dim3(256), 0, stream,
                           h, x, pos, ei, W1, b1, stats, g1, be1, Wg, bg, gate_lin, h_cap);
    } else if (mode == 1) {
        hipLaunchKernelGGL(k_prep, dim3(16), dim3(256), 0, stream, W1, wfrag);
        hipLaunchKernelGGL(k_edge_mfma, dim3(EBM), dim3(256), 0, stream,
                           x, pos, ei, wfrag, b1, stats, deg, h, h_cap);
        hipLaunchKernelGGL(k_bnfin, dim3(1), dim3(64), 0, stream, stats);
        hipLaunchKernelGGL(k_gate<1>, dim3(EB), dim3(256), 0, stream,
                           h, x, pos, ei, W1, b1, stats, g1, be1, Wg, bg, gate_lin, h_cap);
    } else {
        hipLaunchKernelGGL(k_edge<2>, dim3(EB2), dim3(128), 0, stream,
                           x, pos, ei, W1, b1, stats, deg, h, h_cap);
        hipLaunchKernelGGL(k_bnfin, dim3(1), dim3(64), 0, stream, stats);
        hipLaunchKernelGGL(k_gate<2>, dim3(EB), dim3(256), 0, stream,
                           h, x, pos, ei, W1, b1, stats, g1, be1, Wg, bg, gate_lin, h_cap);
    }

    hipLaunchKernelGGL(k_gfin, dim3(1), dim3(64), 0, stream, stats);
    hipLaunchKernelGGL(k_scan, dim3(1), dim3(1024), 0, stream, deg, offs, cursor);
    hipLaunchKernelGGL(k_fill, dim3(EB), dim3(256), 0, stream,
                       ei, cursor, elist, gate_lin, stats, gg, bgb);

    if (mode == 0) {
        hipLaunchKernelGGL(k_aggr<0>, dim3(AB), dim3(256), 0, stream,
                           h, h_cap, gate_lin, offs, elist, ei, x, pos, b1, W1,
                           stats, g1, be1, out);
    } else if (mode == 1) {
        hipLaunchKernelGGL(k_aggr<1>, dim3(AB), dim3(256), 0, stream,
                           h, h_cap, gate_lin, offs, elist, ei, x, pos, b1, W1,
                           stats, g1, be1, out);
    } else {
        hipLaunchKernelGGL(k_aggr<2>, dim3(AB), dim3(256), 0, stream,
                           h, h_cap, gate_lin, offs, elist, ei, x, pos, b1, W1,
                           stats, g1, be1, out);
    }
}